// Round 5
// baseline (375.142 us; speedup 1.0000x reference)
//
#include <hip/hip_runtime.h>
#include <cmath>

#define Tseq 2048
#define Dm   1024
#define NHd  16
#define HDim 64
#define Mrows 4096   // B*T = 2*2048
#define QS   3072    // packed QKV row stride (f16 elems)
#define PAD  72      // LDS row stride (f16) for attention tiles

typedef _Float16 f16;
typedef _Float16 half8 __attribute__((ext_vector_type(8)));
typedef _Float16 half4 __attribute__((ext_vector_type(4)));
typedef float    floatx4 __attribute__((ext_vector_type(4)));

#define ASYNC_COPY16(g, l)                                                       \
  __builtin_amdgcn_global_load_lds((const __attribute__((address_space(1))) void*)(g), \
                                   (__attribute__((address_space(3))) void*)(l), 16, 0, 0)

// tanh-form GELU, one __expf. |err vs exact erf-GELU| <= ~3e-4.
__device__ __forceinline__ float gelu_f(float v) {
  const float u = 0.7978845608028654f * (v + 0.044715f * v * v * v);
  const float e = __expf(2.0f * u);
  return 0.5f * v * (2.0f - 2.0f / (e + 1.0f));
}

// ---------------------------------------------------------------- fused prep
// One launch: 6 weight transposes (f32 -> f16^T) + LN1 (x -> hF).
__device__ __forceinline__ void transp_body(const float* __restrict__ W,
                                            f16* __restrict__ Wt, int K, int N,
                                            int bx, int by, float (*tile)[33]) {
  const int n0 = bx * 32, k0 = by * 32;
  const int tx = threadIdx.x & 31, ty = threadIdx.x >> 5;
#pragma unroll
  for (int i = 0; i < 32; i += 8)
    tile[ty + i][tx] = W[(size_t)(k0 + ty + i) * N + n0 + tx];
  __syncthreads();
#pragma unroll
  for (int i = 0; i < 32; i += 8)
    Wt[(size_t)(n0 + ty + i) * K + k0 + tx] = (f16)tile[tx][ty + i];
}

__global__ __launch_bounds__(256) void prep(const float* __restrict__ Wq,
                                            const float* __restrict__ Wk,
                                            const float* __restrict__ Wv,
                                            const float* __restrict__ Wo,
                                            const float* __restrict__ W1,
                                            const float* __restrict__ W2,
                                            const float* __restrict__ x,
                                            const float* __restrict__ g,
                                            const float* __restrict__ bb,
                                            f16* __restrict__ WqkvT,
                                            f16* __restrict__ WoT,
                                            f16* __restrict__ W1T,
                                            f16* __restrict__ W2T,
                                            f16* __restrict__ hF) {
  __shared__ float tile[32][33];
  __shared__ float red[8];
  const int lin = blockIdx.x;
  if (lin < 4096) {
    const int wsel = lin >> 10, t = lin & 1023;
    const float* W = (wsel == 0) ? Wq : (wsel == 1) ? Wk : (wsel == 2) ? Wv : Wo;
    f16* dst = (wsel < 3) ? (WqkvT + (size_t)wsel * Dm * Dm) : WoT;
    transp_body(W, dst, Dm, Dm, t & 31, t >> 5, tile);
    return;
  }
  if (lin < 8192) {
    const int t = lin - 4096;
    transp_body(W1, W1T, Dm, 4 * Dm, t & 127, t >> 7, tile);
    return;
  }
  if (lin < 12288) {
    const int t = lin - 8192;
    transp_body(W2, W2T, 4 * Dm, Dm, t & 31, t >> 5, tile);
    return;
  }
  // ---- LN1 row
  const int row = lin - 12288, t = threadIdx.x;
  const float4 v = ((const float4*)(x + (size_t)row * Dm))[t];
  float s  = v.x + v.y + v.z + v.w;
  float ss = v.x * v.x + v.y * v.y + v.z * v.z + v.w * v.w;
#pragma unroll
  for (int m = 32; m >= 1; m >>= 1) { s += __shfl_xor(s, m); ss += __shfl_xor(ss, m); }
  if ((t & 63) == 0) { red[t >> 6] = s; red[4 + (t >> 6)] = ss; }
  __syncthreads();
  const float S  = red[0] + red[1] + red[2] + red[3];
  const float SS = red[4] + red[5] + red[6] + red[7];
  const float mean = S * (1.0f / Dm);
  const float inv  = rsqrtf(SS * (1.0f / Dm) - mean * mean + 1e-5f);
  const float4 gg = ((const float4*)g)[t];
  const float4 bv = ((const float4*)bb)[t];
  half4 o;
  o.x = (f16)(((v.x - mean) * inv) * gg.x + bv.x);
  o.y = (f16)(((v.y - mean) * inv) * gg.y + bv.y);
  o.z = (f16)(((v.z - mean) * inv) * gg.z + bv.z);
  o.w = (f16)(((v.w - mean) * inv) * gg.w + bv.w);
  *((half4*)(hF + (size_t)row * Dm) + t) = o;
}

// ---------------------------------------------------------------- split-K reduce (+ fused LN)
template <int NS>
__global__ __launch_bounds__(256) void reduce_ln(const f16* __restrict__ P,
                                                 const float* __restrict__ resid,
                                                 const float* __restrict__ bias,
                                                 const float* __restrict__ g,
                                                 const float* __restrict__ bb,
                                                 float* __restrict__ x1,
                                                 f16* __restrict__ h) {
  const int row = blockIdx.x, t = threadIdx.x;
  const size_t idx = (size_t)row * (Dm / 4) + t;
  const float4 r = ((const float4*)resid)[idx];
  const float4 b = ((const float4*)bias)[t];
  float4 o; o.x = r.x + b.x; o.y = r.y + b.y; o.z = r.z + b.z; o.w = r.w + b.w;
#pragma unroll
  for (int z = 0; z < NS; ++z) {
    const half4 p = ((const half4*)(P + (size_t)z * Mrows * Dm))[idx];
    o.x += (float)p[0]; o.y += (float)p[1]; o.z += (float)p[2]; o.w += (float)p[3];
  }
  ((float4*)x1)[idx] = o;
  float s  = o.x + o.y + o.z + o.w;
  float ss = o.x * o.x + o.y * o.y + o.z * o.z + o.w * o.w;
#pragma unroll
  for (int m = 32; m >= 1; m >>= 1) { s += __shfl_xor(s, m); ss += __shfl_xor(ss, m); }
  __shared__ float red[8];
  if ((t & 63) == 0) { red[t >> 6] = s; red[4 + (t >> 6)] = ss; }
  __syncthreads();
  const float S  = red[0] + red[1] + red[2] + red[3];
  const float SS = red[4] + red[5] + red[6] + red[7];
  const float mean = S * (1.0f / Dm);
  const float inv  = rsqrtf(SS * (1.0f / Dm) - mean * mean + 1e-5f);
  const float4 gg = ((const float4*)g)[t];
  const float4 bv = ((const float4*)bb)[t];
  half4 oh;
  oh[0] = (f16)(((o.x - mean) * inv) * gg.x + bv.x);
  oh[1] = (f16)(((o.y - mean) * inv) * gg.y + bv.y);
  oh[2] = (f16)(((o.z - mean) * inv) * gg.z + bv.z);
  oh[3] = (f16)(((o.w - mean) * inv) * gg.w + bv.w);
  ((half4*)h)[idx] = oh;
}

// plain split-K reduce: out = resid + bias + sum_z P[z]; 16B/lane partial reads (G13)
template <int NS>
__global__ __launch_bounds__(256) void reduceK(const f16* __restrict__ P,
                                               const float* __restrict__ resid,
                                               const float* __restrict__ bias,
                                               float* __restrict__ out) {
  const int t = blockIdx.x * 256 + threadIdx.x;   // 8-f32 group index
  const int col8 = t & (Dm / 8 - 1);
  const float4 r0 = ((const float4*)resid)[2 * t];
  const float4 r1 = ((const float4*)resid)[2 * t + 1];
  const float4 b0 = ((const float4*)bias)[2 * col8];
  const float4 b1 = ((const float4*)bias)[2 * col8 + 1];
  float4 o0, o1;
  o0.x = r0.x + b0.x; o0.y = r0.y + b0.y; o0.z = r0.z + b0.z; o0.w = r0.w + b0.w;
  o1.x = r1.x + b1.x; o1.y = r1.y + b1.y; o1.z = r1.z + b1.z; o1.w = r1.w + b1.w;
#pragma unroll
  for (int z = 0; z < NS; ++z) {
    const half8 p = ((const half8*)(P + (size_t)z * Mrows * Dm))[t];
    o0.x += (float)p[0]; o0.y += (float)p[1]; o0.z += (float)p[2]; o0.w += (float)p[3];
    o1.x += (float)p[4]; o1.y += (float)p[5]; o1.z += (float)p[6]; o1.w += (float)p[7];
  }
  ((float4*)out)[2 * t]     = o0;
  ((float4*)out)[2 * t + 1] = o1;
}

// ---------------------------------------------------------------- GEMM 128x128, BK=64 (f16 MFMA)
// EPI 2: gelu(C+bias)->f16.  EPI 3: C->f16.  EPI 5: f16 partial slab (split-K,
// flat grid, z in low bits).  EPI 2/3: chunked-XCD bx mapping (R4: FFN1 55->45 us,
// B-slab per XCD <=1 MB L2-resident).
template <int EPI, int LNZ>
__global__ __launch_bounds__(256, 4) void gemm_f16(const f16* __restrict__ A,
                                                   const f16* __restrict__ Bt,
                                                   int M, int N, int K, int kLen,
                                                   const float* __restrict__ bias,
                                                   f16* __restrict__ Ch) {
  constexpr int NZ = 1 << LNZ;
  __shared__ f16 As[128 * 64];   // 16 KB
  __shared__ f16 Bs[128 * 64];   // 16 KB
  const int tid = threadIdx.x;
  int bx, by, bz;
  if (EPI == 5) {
    const int lin = blockIdx.x;
    bz = lin & (NZ - 1);
    bx = (lin >> LNZ) & 7;        // N/128 == 8 for these GEMMs
    by = lin >> (LNZ + 3);
  } else {
    const int nbx = N >> 7, chunk = nbx >> 3;
    const int xcd = blockIdx.x & 7, idx = blockIdx.x >> 3;
    bx = xcd * chunk + idx % chunk;
    by = idx / chunk;
    bz = 0;
  }
  const int m0 = by * 128, n0 = bx * 128;
  const int kOff = bz * kLen;
  const int w = tid >> 6, l = tid & 63;
  const int wr = (w >> 1) * 64, wc = (w & 1) * 64;
  const int c = l & 15, qq = l >> 4;
  const int cx = c & 7;            // swizzle key for fragment reads
  const int srow = tid >> 3;       // 0..31 (staging row within 32-row group)
  const int scol = ((tid & 7) ^ (srow & 7)) * 8;  // swizzled global col (f16)

  floatx4 acc[4][4] = {};

  const f16* Ab = A + (size_t)(m0 + srow) * K + kOff + scol;
  const f16* Bb = Bt + (size_t)(n0 + srow) * K + kOff + scol;

  for (int k0 = 0; k0 < kLen; k0 += 64) {
    __syncthreads();
#pragma unroll
    for (int i = 0; i < 4; ++i) {
      ASYNC_COPY16(Ab + k0 + (size_t)(i * 32) * K, As + i * 2048 + w * 512);
      ASYNC_COPY16(Bb + k0 + (size_t)(i * 32) * K, Bs + i * 2048 + w * 512);
    }
    __syncthreads();
    half8 af[4][2], bfr[4][2];
#pragma unroll
    for (int t = 0; t < 4; ++t) {
      const int ra = (wr + t * 16 + c) * 64;
      af[t][0] = *(const half8*)&As[ra + ((qq ^ cx) * 8)];
      af[t][1] = *(const half8*)&As[ra + (((4 + qq) ^ cx) * 8)];
      const int rb = (wc + t * 16 + c) * 64;
      bfr[t][0] = *(const half8*)&Bs[rb + ((qq ^ cx) * 8)];
      bfr[t][1] = *(const half8*)&Bs[rb + (((4 + qq) ^ cx) * 8)];
    }
#pragma unroll
    for (int ti = 0; ti < 4; ++ti)
#pragma unroll
      for (int tj = 0; tj < 4; ++tj) {
        acc[ti][tj] = __builtin_amdgcn_mfma_f32_16x16x32_f16(af[ti][0], bfr[tj][0], acc[ti][tj], 0, 0, 0);
        acc[ti][tj] = __builtin_amdgcn_mfma_f32_16x16x32_f16(af[ti][1], bfr[tj][1], acc[ti][tj], 0, 0, 0);
      }
  }

  f16* Cw = (EPI == 5) ? (Ch + (size_t)bz * M * N) : Ch;
#pragma unroll
  for (int ti = 0; ti < 4; ++ti)
#pragma unroll
    for (int tj = 0; tj < 4; ++tj)
#pragma unroll
      for (int r = 0; r < 4; ++r) {
        const int row = m0 + wr + ti * 16 + qq * 4 + r;
        const int col = n0 + wc + tj * 16 + c;
        const size_t idx = (size_t)row * N + col;
        float v = acc[ti][tj][r];
        if (EPI == 2) {
          Cw[idx] = (f16)gelu_f(v + bias[col]);
        } else {
          Cw[idx] = (f16)v;
        }
      }
}

// ---------------------------------------------------------------- fused attention
// lin in [0,1024):     windowed attention (MFMA), qt = lin&31, (b,h) = lin>>5.
//                      T14 staging: chunk ci+1's K/V global->regs issued during
//                      chunk ci's compute; regs->LDS after the next barrier.
//                      Skips the ii==T-1 store (owned by the global-row blocks).
// lin in [1024,1056):  full global row i = T-1 for one (b,h): scores over all
//                      2048 keys, block softmax, PV — writes row T-1 directly.
__global__ __launch_bounds__(256, 4) void attn_fused(const f16* __restrict__ qkv,
                                                     f16* __restrict__ ao) {
  __shared__ f16 qs[64 * PAD];   // [i][d]
  __shared__ f16 ks[64 * PAD];   // [j][d]
  __shared__ f16 vts[64 * PAD];  // [d][j]  (transposed)
  __shared__ f16 ps[64 * PAD];   // [i][j]  wave-private row slices
  const int lin = blockIdx.x;
  const int tid = threadIdx.x;

  if (lin >= 1024) {
    // ---------------- global row i = T-1, all keys, one block per (b,h)
    const int bh = lin - 1024;
    const int b = bh >> 4, hh = bh & 15;
    const size_t base = ((size_t)b * Tseq) * QS + hh * HDim;
    float* qsh  = (float*)qs;              // 64 floats
    float* psf  = (float*)ps;              // 2048 floats (8 KB <= 9 KB)
    float* red  = (float*)vts;             // 4 + 4
    float* red2 = red + 4;
    float (*oaccp)[64] = (float(*)[64])ks; // 4 x 64 floats
    if (tid < 64) qsh[tid] = (float)qkv[base + (size_t)(Tseq - 1) * QS + tid] * 0.125f;
    __syncthreads();
    float sv[8];
    float mx = -INFINITY;
#pragma unroll
    for (int jj = 0; jj < 8; ++jj) {
      const int j = jj * 256 + tid;
      const f16* kr = qkv + base + 1024 + (size_t)j * QS;
      float a0 = 0.f;
#pragma unroll
      for (int d8 = 0; d8 < 8; ++d8) {
        const half8 kv = *(const half8*)(kr + d8 * 8);
#pragma unroll
        for (int e = 0; e < 8; ++e) a0 = fmaf((float)kv[e], qsh[d8 * 8 + e], a0);
      }
      sv[jj] = a0;
      mx = fmaxf(mx, a0);
    }
#pragma unroll
    for (int mm = 32; mm >= 1; mm >>= 1) mx = fmaxf(mx, __shfl_xor(mx, mm));
    if ((tid & 63) == 0) red[tid >> 6] = mx;
    __syncthreads();
    const float M = fmaxf(fmaxf(red[0], red[1]), fmaxf(red[2], red[3]));
    float sum = 0.f;
#pragma unroll
    for (int jj = 0; jj < 8; ++jj) {
      const float p = __expf(sv[jj] - M);
      psf[jj * 256 + tid] = p;
      sum += p;
    }
#pragma unroll
    for (int mm = 32; mm >= 1; mm >>= 1) sum += __shfl_xor(sum, mm);
    if ((tid & 63) == 0) red2[tid >> 6] = sum;
    __syncthreads();
    const float L = red2[0] + red2[1] + red2[2] + red2[3];
    const int d = tid & 63, pt = tid >> 6;
    const f16* vr = qkv + base + 2048 + d + (size_t)(pt * 512) * QS;
    const float* pp = psf + pt * 512;
    float acc = 0.f;
#pragma unroll 4
    for (int j = 0; j < 512; ++j)
      acc = fmaf(pp[j], (float)vr[(size_t)j * QS], acc);
    oaccp[pt][d] = acc;
    __syncthreads();
    if (tid < 64) {
      const float o = oaccp[0][tid] + oaccp[1][tid] + oaccp[2][tid] + oaccp[3][tid];
      ao[((size_t)(b * Tseq + Tseq - 1)) * Dm + hh * HDim + tid] = (f16)(o / L);
    }
    return;
  }

  // ---------------- windowed attention (MFMA)
  const int qt = lin & 31;
  const int byv = lin >> 5;
  const int b = byv >> 4, hh = byv & 15;
  const int q0 = qt * 64;
  const int w = tid >> 6, l = tid & 63;
  const int c = l & 15, qq = l >> 4;
  const int wr = w * 16;
  const size_t base = ((size_t)b * Tseq) * QS + hh * HDim;
  const int rr = tid >> 2, ss = (tid & 3) * 16;

  {
    const f16* src = qkv + base + (size_t)(q0 + rr) * QS + ss;
    *(uint4*)&qs[rr * PAD + ss]     = *(const uint4*)src;
    *(uint4*)&qs[rr * PAD + ss + 8] = *(const uint4*)(src + 8);
  }

  float m_run[4], l_run[4];
  floatx4 oacc[4];
#pragma unroll
  for (int r = 0; r < 4; ++r) { m_run[r] = -INFINITY; l_run[r] = 0.f; }
#pragma unroll
  for (int td = 0; td < 4; ++td) oacc[td] = (floatx4){0.f, 0.f, 0.f, 0.f};

  int chunks[4]; int nch = 0;
  if (qt > 2) chunks[nch++] = 0;
  for (int ch = (qt - 2 > 0 ? qt - 2 : 0); ch <= qt; ++ch) chunks[nch++] = ch;

  // T14 prologue: chunk 0 K/V -> regs
  uint4 kr0, kr1, vr0, vr1;
  {
    const int j0 = chunks[0] * 64;
    const f16* srck = qkv + base + 1024 + (size_t)(j0 + rr) * QS + ss;
    kr0 = *(const uint4*)srck;
    kr1 = *(const uint4*)(srck + 8);
    const f16* srcv = qkv + base + 2048 + (size_t)(j0 + rr) * QS + ss;
    vr0 = *(const uint4*)srcv;
    vr1 = *(const uint4*)(srcv + 8);
  }

  for (int ci = 0; ci < nch; ++ci) {
    const int j0 = chunks[ci] * 64;
    __syncthreads();
    {
      *(uint4*)&ks[rr * PAD + ss]     = kr0;
      *(uint4*)&ks[rr * PAD + ss + 8] = kr1;
      const f16* e0 = (const f16*)&vr0;
      const f16* e1 = (const f16*)&vr1;
#pragma unroll
      for (int i = 0; i < 8; ++i) vts[(ss + i) * PAD + rr] = e0[i];
#pragma unroll
      for (int i = 0; i < 8; ++i) vts[(ss + 8 + i) * PAD + rr] = e1[i];
    }
    __syncthreads();
    // issue next chunk's loads now; latency hides under this chunk's compute
    if (ci + 1 < nch) {
      const int j1 = chunks[ci + 1] * 64;
      const f16* srck = qkv + base + 1024 + (size_t)(j1 + rr) * QS + ss;
      kr0 = *(const uint4*)srck;
      kr1 = *(const uint4*)(srck + 8);
      const f16* srcv = qkv + base + 2048 + (size_t)(j1 + rr) * QS + ss;
      vr0 = *(const uint4*)srcv;
      vr1 = *(const uint4*)(srcv + 8);
    }

    const half8 a0 = *(const half8*)&qs[(wr + c) * PAD + qq * 8];
    const half8 a1 = *(const half8*)&qs[(wr + c) * PAD + 32 + qq * 8];
    floatx4 sacc[4];
#pragma unroll
    for (int tj = 0; tj < 4; ++tj) {
      const half8 b0 = *(const half8*)&ks[(tj * 16 + c) * PAD + qq * 8];
      const half8 b1 = *(const half8*)&ks[(tj * 16 + c) * PAD + 32 + qq * 8];
      floatx4 s4 = {0.f, 0.f, 0.f, 0.f};
      s4 = __builtin_amdgcn_mfma_f32_16x16x32_f16(a0, b0, s4, 0, 0, 0);
      s4 = __builtin_amdgcn_mfma_f32_16x16x32_f16(a1, b1, s4, 0, 0, 0);
      sacc[tj] = s4;
    }

#pragma unroll
    for (int r = 0; r < 4; ++r) {
      const int ii = q0 + wr + qq * 4 + r;
      float sv[4];
      float mx = -INFINITY;
#pragma unroll
      for (int tj = 0; tj < 4; ++tj) {
        const int jj = j0 + tj * 16 + c;
        const bool allowed = (jj <= ii) && ((ii - jj) <= 128 || jj == 0);
        sv[tj] = allowed ? sacc[tj][r] * 0.125f : -INFINITY;
        mx = fmaxf(mx, sv[tj]);
      }
#pragma unroll
      for (int mm = 8; mm >= 1; mm >>= 1) mx = fmaxf(mx, __shfl_xor(mx, mm));
      const float mn = fmaxf(m_run[r], mx);
      const float alpha = (mn == -INFINITY) ? 1.f : __expf(m_run[r] - mn);
      float sum = 0.f;
      float p[4];
#pragma unroll
      for (int tj = 0; tj < 4; ++tj) { p[tj] = __expf(sv[tj] - mn); sum += p[tj]; }
#pragma unroll
      for (int mm = 8; mm >= 1; mm >>= 1) sum += __shfl_xor(sum, mm);
      l_run[r] = l_run[r] * alpha + sum;
      m_run[r] = mn;
#pragma unroll
      for (int td = 0; td < 4; ++td) oacc[td][r] *= alpha;
#pragma unroll
      for (int tj = 0; tj < 4; ++tj)
        ps[(wr + qq * 4 + r) * PAD + tj * 16 + c] = (f16)p[tj];
    }

    const half8 p0 = *(const half8*)&ps[(wr + c) * PAD + qq * 8];
    const half8 p1 = *(const half8*)&ps[(wr + c) * PAD + 32 + qq * 8];
#pragma unroll
    for (int td = 0; td < 4; ++td) {
      const half8 b0 = *(const half8*)&vts[(td * 16 + c) * PAD + qq * 8];
      const half8 b1 = *(const half8*)&vts[(td * 16 + c) * PAD + 32 + qq * 8];
      oacc[td] = __builtin_amdgcn_mfma_f32_16x16x32_f16(p0, b0, oacc[td], 0, 0, 0);
      oacc[td] = __builtin_amdgcn_mfma_f32_16x16x32_f16(p1, b1, oacc[td], 0, 0, 0);
    }
  }

#pragma unroll
  for (int td = 0; td < 4; ++td)
#pragma unroll
    for (int r = 0; r < 4; ++r) {
      const int ii = q0 + wr + qq * 4 + r;
      if (ii != Tseq - 1)   // row T-1 owned by the global-row blocks
        ao[((size_t)(b * Tseq + ii)) * Dm + hh * HDim + td * 16 + c] =
            (f16)(oacc[td][r] / l_run[r]);
    }
}

// ---------------------------------------------------------------- launch
extern "C" void kernel_launch(void* const* d_in, const int* in_sizes, int n_in,
                              void* d_out, int out_size, void* d_ws, size_t ws_size,
                              hipStream_t stream) {
  (void)in_sizes; (void)n_in; (void)out_size; (void)ws_size;
  const float* x    = (const float*)d_in[0];
  const float* ln1g = (const float*)d_in[1];
  const float* ln1b = (const float*)d_in[2];
  const float* ln2g = (const float*)d_in[3];
  const float* ln2b = (const float*)d_in[4];
  const float* Wq   = (const float*)d_in[5];
  const float* Wk   = (const float*)d_in[6];
  const float* Wv   = (const float*)d_in[7];
  const float* Wo   = (const float*)d_in[8];
  const float* bo   = (const float*)d_in[9];
  const float* W1   = (const float*)d_in[10];
  const float* b1   = (const float*)d_in[11];
  const float* W2   = (const float*)d_in[12];
  const float* b2   = (const float*)d_in[13];
  float* out = (float*)d_out;

  char* w0 = (char*)d_ws;
  size_t off = 0;
  auto take = [&](size_t bytes) -> char* {
    char* p = w0 + off;
    off += (bytes + 255) & ~(size_t)255;
    return p;
  };
  f16*   WqkvT = (f16*)take((size_t)3 * Dm * Dm * 2);  // Wq^T | Wk^T | Wv^T stacked
  f16*   WoT   = (f16*)take((size_t)Dm * Dm * 2);
  f16*   W1T   = (f16*)take((size_t)Dm * 4 * Dm * 2);
  f16*   W2T   = (f16*)take((size_t)Dm * 4 * Dm * 2);
  f16*   hF    = (f16*)take((size_t)Mrows * Dm * 2);
  f16*   qkvh  = (f16*)take((size_t)Mrows * QS * 2);   // 24 MiB
  f16*   attnF = (f16*)take((size_t)Mrows * Dm * 2);   // 8 MiB, contiguous after qkvh
  float* x1    = (float*)take((size_t)Mrows * Dm * 4);
  f16*   h2F   = (f16*)take((size_t)Mrows * Dm * 2);
  f16*   pbuf  = (f16*)take((size_t)4 * Mrows * Dm * 2);  // split-K f16 partials (32 MB)
  f16*   ffn1F = qkvh;  // 4096x4096 f16 = 32 MiB == qkvh(24) + attnF(8) span

  const dim3 blk(256);

  // prep: 6 transposes + LN1 in one launch (16384 blocks)
  prep<<<dim3(16384), blk, 0, stream>>>(Wq, Wk, Wv, Wo, W1, W2, x, ln1g, ln1b,
                                        WqkvT, WoT, W1T, W2T, hF);

  // fused QKV: (4096x1024)@(1024x3072) -> qkvh; 768 blocks, chunked-XCD bx
  gemm_f16<3, 0><<<dim3(768), blk, 0, stream>>>(
      hF, WqkvT, Mrows, QS, Dm, Dm, nullptr, qkvh);

  // attention: windowed (1024) + per-(b,h) global-row blocks (32), one launch
  attn_fused<<<dim3(1056), blk, 0, stream>>>(qkvh, attnF);

  // Wo: split-K2 f16 partials, flat grid with z in low bits (512 blocks)
  gemm_f16<5, 1><<<dim3(512), blk, 0, stream>>>(
      attnF, WoT, Mrows, Dm, Dm, Dm / 2, nullptr, pbuf);
  reduce_ln<2><<<Mrows, blk, 0, stream>>>(pbuf, x, bo, ln2g, ln2b, x1, h2F);

  // FFN1: N=4096, 1024 blocks, chunked-XCD bx, fast-GELU epilogue
  gemm_f16<2, 0><<<dim3(1024), blk, 0, stream>>>(
      h2F, W1T, Mrows, 4 * Dm, Dm, Dm, b1, ffn1F);

  // W2: split-K4 f16 partials, flat grid (1024 blocks), then out = x1 + b2 + sum(P)
  gemm_f16<5, 2><<<dim3(1024), blk, 0, stream>>>(
      ffn1F, W2T, Mrows, Dm, 4 * Dm, Dm, nullptr, pbuf);
  reduceK<4><<<Mrows * Dm / (256 * 8), blk, 0, stream>>>(pbuf, x1, b2, out);
}

// Round 6
// 328.629 us; speedup vs baseline: 1.1415x; 1.1415x over previous
//
#include <hip/hip_runtime.h>
#include <cmath>

#define Tseq 2048
#define Dm   1024
#define NHd  16
#define HDim 64
#define Mrows 4096   // B*T = 2*2048
#define QS   3072    // packed QKV row stride (f16 elems)
#define PAD  72      // LDS row stride (f16) for attention tiles
#define NSPLIT 16    // j-splits for the global row (i = T-1)

typedef _Float16 f16;
typedef _Float16 half8 __attribute__((ext_vector_type(8)));
typedef _Float16 half4 __attribute__((ext_vector_type(4)));
typedef float    floatx4 __attribute__((ext_vector_type(4)));

#define ASYNC_COPY16(g, l)                                                       \
  __builtin_amdgcn_global_load_lds((const __attribute__((address_space(1))) void*)(g), \
                                   (__attribute__((address_space(3))) void*)(l), 16, 0, 0)

// tanh-form GELU, one __expf. |err vs exact erf-GELU| <= ~3e-4.
__device__ __forceinline__ float gelu_f(float v) {
  const float u = 0.7978845608028654f * (v + 0.044715f * v * v * v);
  const float e = __expf(2.0f * u);
  return 0.5f * v * (2.0f - 2.0f / (e + 1.0f));
}

// ---------------------------------------------------------------- fused prep
// One launch: 6 weight transposes (f32 -> f16^T) + LN1 (x -> hF).
__device__ __forceinline__ void transp_body(const float* __restrict__ W,
                                            f16* __restrict__ Wt, int K, int N,
                                            int bx, int by, float (*tile)[33]) {
  const int n0 = bx * 32, k0 = by * 32;
  const int tx = threadIdx.x & 31, ty = threadIdx.x >> 5;
#pragma unroll
  for (int i = 0; i < 32; i += 8)
    tile[ty + i][tx] = W[(size_t)(k0 + ty + i) * N + n0 + tx];
  __syncthreads();
#pragma unroll
  for (int i = 0; i < 32; i += 8)
    Wt[(size_t)(n0 + ty + i) * K + k0 + tx] = (f16)tile[tx][ty + i];
}

__global__ __launch_bounds__(256) void prep(const float* __restrict__ Wq,
                                            const float* __restrict__ Wk,
                                            const float* __restrict__ Wv,
                                            const float* __restrict__ Wo,
                                            const float* __restrict__ W1,
                                            const float* __restrict__ W2,
                                            const float* __restrict__ x,
                                            const float* __restrict__ g,
                                            const float* __restrict__ bb,
                                            f16* __restrict__ WqkvT,
                                            f16* __restrict__ WoT,
                                            f16* __restrict__ W1T,
                                            f16* __restrict__ W2T,
                                            f16* __restrict__ hF) {
  __shared__ float tile[32][33];
  __shared__ float red[8];
  const int lin = blockIdx.x;
  if (lin < 4096) {
    const int wsel = lin >> 10, t = lin & 1023;
    const float* W = (wsel == 0) ? Wq : (wsel == 1) ? Wk : (wsel == 2) ? Wv : Wo;
    f16* dst = (wsel < 3) ? (WqkvT + (size_t)wsel * Dm * Dm) : WoT;
    transp_body(W, dst, Dm, Dm, t & 31, t >> 5, tile);
    return;
  }
  if (lin < 8192) {
    const int t = lin - 4096;
    transp_body(W1, W1T, Dm, 4 * Dm, t & 127, t >> 7, tile);
    return;
  }
  if (lin < 12288) {
    const int t = lin - 8192;
    transp_body(W2, W2T, 4 * Dm, Dm, t & 31, t >> 5, tile);
    return;
  }
  // ---- LN1 row
  const int row = lin - 12288, t = threadIdx.x;
  const float4 v = ((const float4*)(x + (size_t)row * Dm))[t];
  float s  = v.x + v.y + v.z + v.w;
  float ss = v.x * v.x + v.y * v.y + v.z * v.z + v.w * v.w;
#pragma unroll
  for (int m = 32; m >= 1; m >>= 1) { s += __shfl_xor(s, m); ss += __shfl_xor(ss, m); }
  if ((t & 63) == 0) { red[t >> 6] = s; red[4 + (t >> 6)] = ss; }
  __syncthreads();
  const float S  = red[0] + red[1] + red[2] + red[3];
  const float SS = red[4] + red[5] + red[6] + red[7];
  const float mean = S * (1.0f / Dm);
  const float inv  = rsqrtf(SS * (1.0f / Dm) - mean * mean + 1e-5f);
  const float4 gg = ((const float4*)g)[t];
  const float4 bv = ((const float4*)bb)[t];
  half4 o;
  o.x = (f16)(((v.x - mean) * inv) * gg.x + bv.x);
  o.y = (f16)(((v.y - mean) * inv) * gg.y + bv.y);
  o.z = (f16)(((v.z - mean) * inv) * gg.z + bv.z);
  o.w = (f16)(((v.w - mean) * inv) * gg.w + bv.w);
  *((half4*)(hF + (size_t)row * Dm) + t) = o;
}

// ---------------------------------------------------------------- split-K reduce (+ fused LN)
template <int NS>
__global__ __launch_bounds__(256) void reduce_ln(const f16* __restrict__ P,
                                                 const float* __restrict__ resid,
                                                 const float* __restrict__ bias,
                                                 const float* __restrict__ g,
                                                 const float* __restrict__ bb,
                                                 float* __restrict__ x1,
                                                 f16* __restrict__ h) {
  const int row = blockIdx.x, t = threadIdx.x;
  const size_t idx = (size_t)row * (Dm / 4) + t;
  const float4 r = ((const float4*)resid)[idx];
  const float4 b = ((const float4*)bias)[t];
  float4 o; o.x = r.x + b.x; o.y = r.y + b.y; o.z = r.z + b.z; o.w = r.w + b.w;
#pragma unroll
  for (int z = 0; z < NS; ++z) {
    const half4 p = ((const half4*)(P + (size_t)z * Mrows * Dm))[idx];
    o.x += (float)p[0]; o.y += (float)p[1]; o.z += (float)p[2]; o.w += (float)p[3];
  }
  ((float4*)x1)[idx] = o;
  float s  = o.x + o.y + o.z + o.w;
  float ss = o.x * o.x + o.y * o.y + o.z * o.z + o.w * o.w;
#pragma unroll
  for (int m = 32; m >= 1; m >>= 1) { s += __shfl_xor(s, m); ss += __shfl_xor(ss, m); }
  __shared__ float red[8];
  if ((t & 63) == 0) { red[t >> 6] = s; red[4 + (t >> 6)] = ss; }
  __syncthreads();
  const float S  = red[0] + red[1] + red[2] + red[3];
  const float SS = red[4] + red[5] + red[6] + red[7];
  const float mean = S * (1.0f / Dm);
  const float inv  = rsqrtf(SS * (1.0f / Dm) - mean * mean + 1e-5f);
  const float4 gg = ((const float4*)g)[t];
  const float4 bv = ((const float4*)bb)[t];
  half4 oh;
  oh[0] = (f16)(((o.x - mean) * inv) * gg.x + bv.x);
  oh[1] = (f16)(((o.y - mean) * inv) * gg.y + bv.y);
  oh[2] = (f16)(((o.z - mean) * inv) * gg.z + bv.z);
  oh[3] = (f16)(((o.w - mean) * inv) * gg.w + bv.w);
  ((half4*)h)[idx] = oh;
}

// plain split-K reduce: out = resid + bias + sum_z P[z]; 16B/lane partial reads (G13)
template <int NS>
__global__ __launch_bounds__(256) void reduceK(const f16* __restrict__ P,
                                               const float* __restrict__ resid,
                                               const float* __restrict__ bias,
                                               float* __restrict__ out) {
  const int t = blockIdx.x * 256 + threadIdx.x;   // 8-f32 group index
  const int col8 = t & (Dm / 8 - 1);
  const float4 r0 = ((const float4*)resid)[2 * t];
  const float4 r1 = ((const float4*)resid)[2 * t + 1];
  const float4 b0 = ((const float4*)bias)[2 * col8];
  const float4 b1 = ((const float4*)bias)[2 * col8 + 1];
  float4 o0, o1;
  o0.x = r0.x + b0.x; o0.y = r0.y + b0.y; o0.z = r0.z + b0.z; o0.w = r0.w + b0.w;
  o1.x = r1.x + b1.x; o1.y = r1.y + b1.y; o1.z = r1.z + b1.z; o1.w = r1.w + b1.w;
#pragma unroll
  for (int z = 0; z < NS; ++z) {
    const half8 p = ((const half8*)(P + (size_t)z * Mrows * Dm))[t];
    o0.x += (float)p[0]; o0.y += (float)p[1]; o0.z += (float)p[2]; o0.w += (float)p[3];
    o1.x += (float)p[4]; o1.y += (float)p[5]; o1.z += (float)p[6]; o1.w += (float)p[7];
  }
  ((float4*)out)[2 * t]     = o0;
  ((float4*)out)[2 * t + 1] = o1;
}

// ---------------------------------------------------------------- GEMM 128x128, BK=64 (f16 MFMA)
// EPI 2: gelu(C+bias)->f16.  EPI 3: C->f16.  EPI 5: f16 partial slab (split-K,
// flat grid, z in low bits).  EPI 2/3: chunked-XCD bx mapping (R4: FFN1 55->45 us,
// B-slab per XCD <=1 MB L2-resident).
template <int EPI, int LNZ>
__global__ __launch_bounds__(256, 4) void gemm_f16(const f16* __restrict__ A,
                                                   const f16* __restrict__ Bt,
                                                   int M, int N, int K, int kLen,
                                                   const float* __restrict__ bias,
                                                   f16* __restrict__ Ch) {
  constexpr int NZ = 1 << LNZ;
  __shared__ f16 As[128 * 64];   // 16 KB
  __shared__ f16 Bs[128 * 64];   // 16 KB
  const int tid = threadIdx.x;
  int bx, by, bz;
  if (EPI == 5) {
    const int lin = blockIdx.x;
    bz = lin & (NZ - 1);
    bx = (lin >> LNZ) & 7;        // N/128 == 8 for these GEMMs
    by = lin >> (LNZ + 3);
  } else {
    const int nbx = N >> 7, chunk = nbx >> 3;
    const int xcd = blockIdx.x & 7, idx = blockIdx.x >> 3;
    bx = xcd * chunk + idx % chunk;
    by = idx / chunk;
    bz = 0;
  }
  const int m0 = by * 128, n0 = bx * 128;
  const int kOff = bz * kLen;
  const int w = tid >> 6, l = tid & 63;
  const int wr = (w >> 1) * 64, wc = (w & 1) * 64;
  const int c = l & 15, qq = l >> 4;
  const int cx = c & 7;            // swizzle key for fragment reads
  const int srow = tid >> 3;       // 0..31 (staging row within 32-row group)
  const int scol = ((tid & 7) ^ (srow & 7)) * 8;  // swizzled global col (f16)

  floatx4 acc[4][4] = {};

  const f16* Ab = A + (size_t)(m0 + srow) * K + kOff + scol;
  const f16* Bb = Bt + (size_t)(n0 + srow) * K + kOff + scol;

  for (int k0 = 0; k0 < kLen; k0 += 64) {
    __syncthreads();
#pragma unroll
    for (int i = 0; i < 4; ++i) {
      ASYNC_COPY16(Ab + k0 + (size_t)(i * 32) * K, As + i * 2048 + w * 512);
      ASYNC_COPY16(Bb + k0 + (size_t)(i * 32) * K, Bs + i * 2048 + w * 512);
    }
    __syncthreads();
    half8 af[4][2], bfr[4][2];
#pragma unroll
    for (int t = 0; t < 4; ++t) {
      const int ra = (wr + t * 16 + c) * 64;
      af[t][0] = *(const half8*)&As[ra + ((qq ^ cx) * 8)];
      af[t][1] = *(const half8*)&As[ra + (((4 + qq) ^ cx) * 8)];
      const int rb = (wc + t * 16 + c) * 64;
      bfr[t][0] = *(const half8*)&Bs[rb + ((qq ^ cx) * 8)];
      bfr[t][1] = *(const half8*)&Bs[rb + (((4 + qq) ^ cx) * 8)];
    }
#pragma unroll
    for (int ti = 0; ti < 4; ++ti)
#pragma unroll
      for (int tj = 0; tj < 4; ++tj) {
        acc[ti][tj] = __builtin_amdgcn_mfma_f32_16x16x32_f16(af[ti][0], bfr[tj][0], acc[ti][tj], 0, 0, 0);
        acc[ti][tj] = __builtin_amdgcn_mfma_f32_16x16x32_f16(af[ti][1], bfr[tj][1], acc[ti][tj], 0, 0, 0);
      }
  }

  f16* Cw = (EPI == 5) ? (Ch + (size_t)bz * M * N) : Ch;
#pragma unroll
  for (int ti = 0; ti < 4; ++ti)
#pragma unroll
    for (int tj = 0; tj < 4; ++tj)
#pragma unroll
      for (int r = 0; r < 4; ++r) {
        const int row = m0 + wr + ti * 16 + qq * 4 + r;
        const int col = n0 + wc + tj * 16 + c;
        const size_t idx = (size_t)row * N + col;
        float v = acc[ti][tj][r];
        if (EPI == 2) {
          Cw[idx] = (f16)gelu_f(v + bias[col]);
        } else {
          Cw[idx] = (f16)v;
        }
      }
}

// ---------------------------------------------------------------- fused attention
// R4 structure (restored): lin in [0,1024) windowed MFMA blocks; lin in
// [1024,1536) global-row T-1 partials (split-j over 16 splits — keeps the tail
// phase 512-way block-parallel; R5's 32-block fold made it a 60 us serial tail).
__global__ __launch_bounds__(256, 4) void attn_fused(const f16* __restrict__ qkv,
                                                     f16* __restrict__ ao,
                                                     float* __restrict__ part) {
  __shared__ f16 qs[64 * PAD];   // [i][d]
  __shared__ f16 ks[64 * PAD];   // [j][d]
  __shared__ f16 vts[64 * PAD];  // [d][j]  (transposed)
  __shared__ f16 ps[64 * PAD];   // [i][j]  wave-private row slices
  const int lin = blockIdx.x;
  const int tid = threadIdx.x;

  if (lin >= 1024) {
    // ---------------- global row i = T-1 (split-j), LDS overlaid on attn tiles
    const int r_ = lin - 1024;
    const int bh = r_ & 31, sp = r_ >> 5;
    const int b = bh >> 4, hh = bh & 15;
    const size_t base = ((size_t)b * Tseq) * QS + hh * HDim;
    const int j0 = sp * (Tseq / NSPLIT);   // 128 keys per split
    float* qsh  = (float*)qs;              // 64 floats
    float* psf  = (float*)ks;              // 128 floats
    float* red  = (float*)vts;             // 4
    float* red2 = red + 4;                 // 4
    float (*oaccp)[64] = (float(*)[64])ps; // 4 x 64 floats
    if (tid < 64) qsh[tid] = (float)qkv[base + (size_t)(Tseq - 1) * QS + tid] * 0.125f;
    __syncthreads();
    float sv = -INFINITY;
    if (tid < 128) {
      const f16* kr = qkv + base + 1024 + (size_t)(j0 + tid) * QS;
      float a0 = 0.f;
#pragma unroll
      for (int d8 = 0; d8 < 8; ++d8) {
        const half8 kv = *(const half8*)(kr + d8 * 8);
#pragma unroll
        for (int e = 0; e < 8; ++e) a0 = fmaf((float)kv[e], qsh[d8 * 8 + e], a0);
      }
      sv = a0;  // row T-1: all j <= T-1 allowed
    }
    float mx = sv;
#pragma unroll
    for (int mm = 32; mm >= 1; mm >>= 1) mx = fmaxf(mx, __shfl_xor(mx, mm));
    if ((tid & 63) == 0) red[tid >> 6] = mx;
    __syncthreads();
    const float M = fmaxf(red[0], red[1]);  // waves 2,3 hold -inf
    float p = 0.f;
    if (tid < 128) { p = __expf(sv - M); psf[tid] = p; }
    float sum = p;
#pragma unroll
    for (int mm = 32; mm >= 1; mm >>= 1) sum += __shfl_xor(sum, mm);
    if ((tid & 63) == 0) red2[tid >> 6] = sum;
    __syncthreads();
    const float L = red2[0] + red2[1];
    const int d = tid & 63, pt = tid >> 6;
    const f16* vb = qkv + base + 2048 + d;
    float acc = 0.f;
    for (int j = pt * 32; j < pt * 32 + 32; ++j)
      acc = fmaf(psf[j], (float)vb[(size_t)(j0 + j) * QS], acc);
    oaccp[pt][d] = acc;
    __syncthreads();
    if (tid < 64) {
      const float o = oaccp[0][tid] + oaccp[1][tid] + oaccp[2][tid] + oaccp[3][tid];
      float* dst = part + ((size_t)bh * NSPLIT + sp) * 66;
      dst[tid] = o;
      if (tid == 0) { dst[64] = M; dst[65] = L; }
    }
    return;
  }

  // ---------------- windowed attention (MFMA)
  const int qt = lin & 31;
  const int byv = lin >> 5;
  const int b = byv >> 4, hh = byv & 15;
  const int q0 = qt * 64;
  const int w = tid >> 6, l = tid & 63;
  const int c = l & 15, qq = l >> 4;
  const int wr = w * 16;
  const size_t base = ((size_t)b * Tseq) * QS + hh * HDim;
  const int rr = tid >> 2, ss = (tid & 3) * 16;

  {
    const f16* src = qkv + base + (size_t)(q0 + rr) * QS + ss;
    *(uint4*)&qs[rr * PAD + ss]     = *(const uint4*)src;
    *(uint4*)&qs[rr * PAD + ss + 8] = *(const uint4*)(src + 8);
  }

  float m_run[4], l_run[4];
  floatx4 oacc[4];
#pragma unroll
  for (int r = 0; r < 4; ++r) { m_run[r] = -INFINITY; l_run[r] = 0.f; }
#pragma unroll
  for (int td = 0; td < 4; ++td) oacc[td] = (floatx4){0.f, 0.f, 0.f, 0.f};

  int chunks[4]; int nch = 0;
  if (qt > 2) chunks[nch++] = 0;
  for (int ch = (qt - 2 > 0 ? qt - 2 : 0); ch <= qt; ++ch) chunks[nch++] = ch;

  for (int ci = 0; ci < nch; ++ci) {
    const int j0 = chunks[ci] * 64;
    __syncthreads();
    {
      const f16* srck = qkv + base + 1024 + (size_t)(j0 + rr) * QS + ss;
      *(uint4*)&ks[rr * PAD + ss]     = *(const uint4*)srck;
      *(uint4*)&ks[rr * PAD + ss + 8] = *(const uint4*)(srck + 8);
      const f16* srcv = qkv + base + 2048 + (size_t)(j0 + rr) * QS + ss;
      uint4 va0 = *(const uint4*)srcv;
      uint4 va1 = *(const uint4*)(srcv + 8);
      const f16* e0 = (const f16*)&va0;
      const f16* e1 = (const f16*)&va1;
#pragma unroll
      for (int i = 0; i < 8; ++i) vts[(ss + i) * PAD + rr] = e0[i];
#pragma unroll
      for (int i = 0; i < 8; ++i) vts[(ss + 8 + i) * PAD + rr] = e1[i];
    }
    __syncthreads();

    const half8 a0 = *(const half8*)&qs[(wr + c) * PAD + qq * 8];
    const half8 a1 = *(const half8*)&qs[(wr + c) * PAD + 32 + qq * 8];
    floatx4 sacc[4];
#pragma unroll
    for (int tj = 0; tj < 4; ++tj) {
      const half8 b0 = *(const half8*)&ks[(tj * 16 + c) * PAD + qq * 8];
      const half8 b1 = *(const half8*)&ks[(tj * 16 + c) * PAD + 32 + qq * 8];
      floatx4 s4 = {0.f, 0.f, 0.f, 0.f};
      s4 = __builtin_amdgcn_mfma_f32_16x16x32_f16(a0, b0, s4, 0, 0, 0);
      s4 = __builtin_amdgcn_mfma_f32_16x16x32_f16(a1, b1, s4, 0, 0, 0);
      sacc[tj] = s4;
    }

#pragma unroll
    for (int r = 0; r < 4; ++r) {
      const int ii = q0 + wr + qq * 4 + r;
      float sv[4];
      float mx = -INFINITY;
#pragma unroll
      for (int tj = 0; tj < 4; ++tj) {
        const int jj = j0 + tj * 16 + c;
        const bool allowed = (jj <= ii) && ((ii - jj) <= 128 || jj == 0);
        sv[tj] = allowed ? sacc[tj][r] * 0.125f : -INFINITY;
        mx = fmaxf(mx, sv[tj]);
      }
#pragma unroll
      for (int mm = 8; mm >= 1; mm >>= 1) mx = fmaxf(mx, __shfl_xor(mx, mm));
      const float mn = fmaxf(m_run[r], mx);
      const float alpha = (mn == -INFINITY) ? 1.f : __expf(m_run[r] - mn);
      float sum = 0.f;
      float p[4];
#pragma unroll
      for (int tj = 0; tj < 4; ++tj) { p[tj] = __expf(sv[tj] - mn); sum += p[tj]; }
#pragma unroll
      for (int mm = 8; mm >= 1; mm >>= 1) sum += __shfl_xor(sum, mm);
      l_run[r] = l_run[r] * alpha + sum;
      m_run[r] = mn;
#pragma unroll
      for (int td = 0; td < 4; ++td) oacc[td][r] *= alpha;
#pragma unroll
      for (int tj = 0; tj < 4; ++tj)
        ps[(wr + qq * 4 + r) * PAD + tj * 16 + c] = (f16)p[tj];
    }

    const half8 p0 = *(const half8*)&ps[(wr + c) * PAD + qq * 8];
    const half8 p1 = *(const half8*)&ps[(wr + c) * PAD + 32 + qq * 8];
#pragma unroll
    for (int td = 0; td < 4; ++td) {
      const half8 b0 = *(const half8*)&vts[(td * 16 + c) * PAD + qq * 8];
      const half8 b1 = *(const half8*)&vts[(td * 16 + c) * PAD + 32 + qq * 8];
      oacc[td] = __builtin_amdgcn_mfma_f32_16x16x32_f16(p0, b0, oacc[td], 0, 0, 0);
      oacc[td] = __builtin_amdgcn_mfma_f32_16x16x32_f16(p1, b1, oacc[td], 0, 0, 0);
    }
  }

#pragma unroll
  for (int td = 0; td < 4; ++td)
#pragma unroll
    for (int r = 0; r < 4; ++r) {
      const int ii = q0 + wr + qq * 4 + r;
      ao[((size_t)(b * Tseq + ii)) * Dm + hh * HDim + td * 16 + c] =
          (f16)(oacc[td][r] / l_run[r]);
    }
}

// Combine NSPLIT partials per (b,h) and write row T-1 of attnF.
__global__ __launch_bounds__(64) void attn_row_comb(const float* __restrict__ part,
                                                    f16* __restrict__ ao) {
  const int bh = blockIdx.x;
  const int b = bh >> 4, hh = bh & 15;
  const int tid = threadIdx.x;
  const float* pp = part + (size_t)bh * NSPLIT * 66;
  float M = -INFINITY;
#pragma unroll
  for (int s = 0; s < NSPLIT; ++s) M = fmaxf(M, pp[s * 66 + 64]);
  float L = 0.f, o = 0.f;
#pragma unroll
  for (int s = 0; s < NSPLIT; ++s) {
    const float wgt = __expf(pp[s * 66 + 64] - M);
    L += pp[s * 66 + 65] * wgt;
    o += pp[s * 66 + tid] * wgt;
  }
  ao[((size_t)(b * Tseq + Tseq - 1)) * Dm + hh * HDim + tid] = (f16)(o / L);
}

// ---------------------------------------------------------------- launch
extern "C" void kernel_launch(void* const* d_in, const int* in_sizes, int n_in,
                              void* d_out, int out_size, void* d_ws, size_t ws_size,
                              hipStream_t stream) {
  (void)in_sizes; (void)n_in; (void)out_size; (void)ws_size;
  const float* x    = (const float*)d_in[0];
  const float* ln1g = (const float*)d_in[1];
  const float* ln1b = (const float*)d_in[2];
  const float* ln2g = (const float*)d_in[3];
  const float* ln2b = (const float*)d_in[4];
  const float* Wq   = (const float*)d_in[5];
  const float* Wk   = (const float*)d_in[6];
  const float* Wv   = (const float*)d_in[7];
  const float* Wo   = (const float*)d_in[8];
  const float* bo   = (const float*)d_in[9];
  const float* W1   = (const float*)d_in[10];
  const float* b1   = (const float*)d_in[11];
  const float* W2   = (const float*)d_in[12];
  const float* b2   = (const float*)d_in[13];
  float* out = (float*)d_out;

  char* w0 = (char*)d_ws;
  size_t off = 0;
  auto take = [&](size_t bytes) -> char* {
    char* p = w0 + off;
    off += (bytes + 255) & ~(size_t)255;
    return p;
  };
  f16*   WqkvT = (f16*)take((size_t)3 * Dm * Dm * 2);  // Wq^T | Wk^T | Wv^T stacked
  f16*   WoT   = (f16*)take((size_t)Dm * Dm * 2);
  f16*   W1T   = (f16*)take((size_t)Dm * 4 * Dm * 2);
  f16*   W2T   = (f16*)take((size_t)Dm * 4 * Dm * 2);
  f16*   hF    = (f16*)take((size_t)Mrows * Dm * 2);
  f16*   qkvh  = (f16*)take((size_t)Mrows * QS * 2);   // 24 MiB
  f16*   attnF = (f16*)take((size_t)Mrows * Dm * 2);   // 8 MiB, contiguous after qkvh
  float* x1    = (float*)take((size_t)Mrows * Dm * 4);
  f16*   h2F   = (f16*)take((size_t)Mrows * Dm * 2);
  f16*   pbuf  = (f16*)take((size_t)4 * Mrows * Dm * 2);  // split-K f16 partials (32 MB)
  float* rowp  = (float*)take((size_t)32 * NSPLIT * 66 * 4);  // global-row partials
  f16*   ffn1F = qkvh;  // 4096x4096 f16 = 32 MiB == qkvh(24) + attnF(8) span

  const dim3 blk(256);

  // prep: 6 transposes + LN1 in one launch (16384 blocks)
  prep<<<dim3(16384), blk, 0, stream>>>(Wq, Wk, Wv, Wo, W1, W2, x, ln1g, ln1b,
                                        WqkvT, WoT, W1T, W2T, hF);

  // fused QKV: (4096x1024)@(1024x3072) -> qkvh; 768 blocks, chunked-XCD bx
  gemm_f16<3, 0><<<dim3(768), blk, 0, stream>>>(
      hF, WqkvT, Mrows, QS, Dm, Dm, nullptr, qkvh);

  // attention: windowed (1024) + global-row split-j partials (512), one launch
  attn_fused<<<dim3(1536), blk, 0, stream>>>(qkvh, attnF, rowp);
  attn_row_comb<<<dim3(2 * NHd), dim3(64), 0, stream>>>(rowp, attnF);

  // Wo: split-K2 f16 partials, flat grid with z in low bits (512 blocks)
  gemm_f16<5, 1><<<dim3(512), blk, 0, stream>>>(
      attnF, WoT, Mrows, Dm, Dm, Dm / 2, nullptr, pbuf);
  reduce_ln<2><<<Mrows, blk, 0, stream>>>(pbuf, x, bo, ln2g, ln2b, x1, h2F);

  // FFN1: N=4096, 1024 blocks, chunked-XCD bx, fast-GELU epilogue
  gemm_f16<2, 0><<<dim3(1024), blk, 0, stream>>>(
      h2F, W1T, Mrows, 4 * Dm, Dm, Dm, b1, ffn1F);

  // W2: split-K4 f16 partials, flat grid (1024 blocks), then out = x1 + b2 + sum(P)
  gemm_f16<5, 2><<<dim3(1024), blk, 0, stream>>>(
      ffn1F, W2T, Mrows, Dm, 4 * Dm, Dm, nullptr, pbuf);
  reduceK<4><<<Mrows * Dm / (256 * 8), blk, 0, stream>>>(pbuf, x1, b2, out);
}

// Round 7
// 305.078 us; speedup vs baseline: 1.2297x; 1.0772x over previous
//
#include <hip/hip_runtime.h>
#include <cmath>

#define Tseq 2048
#define Dm   1024
#define NHd  16
#define HDim 64
#define Mrows 4096   // B*T = 2*2048
#define QS   3072    // packed QKV row stride (f16 elems)
#define PAD  72      // LDS row stride (f16) for attention tiles
#define NSPLIT 16    // j-splits for the global row (i = T-1)

typedef _Float16 f16;
typedef _Float16 half8 __attribute__((ext_vector_type(8)));
typedef _Float16 half4 __attribute__((ext_vector_type(4)));
typedef float    floatx4 __attribute__((ext_vector_type(4)));

#define ASYNC_COPY16(g, l)                                                       \
  __builtin_amdgcn_global_load_lds((const __attribute__((address_space(1))) void*)(g), \
                                   (__attribute__((address_space(3))) void*)(l), 16, 0, 0)

// tanh-form GELU, one __expf. |err vs exact erf-GELU| <= ~3e-4.
__device__ __forceinline__ float gelu_f(float v) {
  const float u = 0.7978845608028654f * (v + 0.044715f * v * v * v);
  const float e = __expf(2.0f * u);
  return 0.5f * v * (2.0f - 2.0f / (e + 1.0f));
}

// ---------------------------------------------------------------- fused prep
// One launch: 6 weight transposes (f32 -> f16^T) + LN1 (x -> hF).
__device__ __forceinline__ void transp_body(const float* __restrict__ W,
                                            f16* __restrict__ Wt, int K, int N,
                                            int bx, int by, float (*tile)[33]) {
  const int n0 = bx * 32, k0 = by * 32;
  const int tx = threadIdx.x & 31, ty = threadIdx.x >> 5;
#pragma unroll
  for (int i = 0; i < 32; i += 8)
    tile[ty + i][tx] = W[(size_t)(k0 + ty + i) * N + n0 + tx];
  __syncthreads();
#pragma unroll
  for (int i = 0; i < 32; i += 8)
    Wt[(size_t)(n0 + ty + i) * K + k0 + tx] = (f16)tile[tx][ty + i];
}

__global__ __launch_bounds__(256) void prep(const float* __restrict__ Wq,
                                            const float* __restrict__ Wk,
                                            const float* __restrict__ Wv,
                                            const float* __restrict__ Wo,
                                            const float* __restrict__ W1,
                                            const float* __restrict__ W2,
                                            const float* __restrict__ x,
                                            const float* __restrict__ g,
                                            const float* __restrict__ bb,
                                            f16* __restrict__ WqkvT,
                                            f16* __restrict__ WoT,
                                            f16* __restrict__ W1T,
                                            f16* __restrict__ W2T,
                                            f16* __restrict__ hF) {
  __shared__ float tile[32][33];
  __shared__ float red[8];
  const int lin = blockIdx.x;
  if (lin < 4096) {
    const int wsel = lin >> 10, t = lin & 1023;
    const float* W = (wsel == 0) ? Wq : (wsel == 1) ? Wk : (wsel == 2) ? Wv : Wo;
    f16* dst = (wsel < 3) ? (WqkvT + (size_t)wsel * Dm * Dm) : WoT;
    transp_body(W, dst, Dm, Dm, t & 31, t >> 5, tile);
    return;
  }
  if (lin < 8192) {
    const int t = lin - 4096;
    transp_body(W1, W1T, Dm, 4 * Dm, t & 127, t >> 7, tile);
    return;
  }
  if (lin < 12288) {
    const int t = lin - 8192;
    transp_body(W2, W2T, 4 * Dm, Dm, t & 31, t >> 5, tile);
    return;
  }
  // ---- LN1 row
  const int row = lin - 12288, t = threadIdx.x;
  const float4 v = ((const float4*)(x + (size_t)row * Dm))[t];
  float s  = v.x + v.y + v.z + v.w;
  float ss = v.x * v.x + v.y * v.y + v.z * v.z + v.w * v.w;
#pragma unroll
  for (int m = 32; m >= 1; m >>= 1) { s += __shfl_xor(s, m); ss += __shfl_xor(ss, m); }
  if ((t & 63) == 0) { red[t >> 6] = s; red[4 + (t >> 6)] = ss; }
  __syncthreads();
  const float S  = red[0] + red[1] + red[2] + red[3];
  const float SS = red[4] + red[5] + red[6] + red[7];
  const float mean = S * (1.0f / Dm);
  const float inv  = rsqrtf(SS * (1.0f / Dm) - mean * mean + 1e-5f);
  const float4 gg = ((const float4*)g)[t];
  const float4 bv = ((const float4*)bb)[t];
  half4 o;
  o.x = (f16)(((v.x - mean) * inv) * gg.x + bv.x);
  o.y = (f16)(((v.y - mean) * inv) * gg.y + bv.y);
  o.z = (f16)(((v.z - mean) * inv) * gg.z + bv.z);
  o.w = (f16)(((v.w - mean) * inv) * gg.w + bv.w);
  *((half4*)(hF + (size_t)row * Dm) + t) = o;
}

// ---------------------------------------------------------------- split-K reduce (+ fused LN)
template <int NS>
__global__ __launch_bounds__(256) void reduce_ln(const f16* __restrict__ P,
                                                 const float* __restrict__ resid,
                                                 const float* __restrict__ bias,
                                                 const float* __restrict__ g,
                                                 const float* __restrict__ bb,
                                                 float* __restrict__ x1,
                                                 f16* __restrict__ h) {
  const int row = blockIdx.x, t = threadIdx.x;
  const size_t idx = (size_t)row * (Dm / 4) + t;
  const float4 r = ((const float4*)resid)[idx];
  const float4 b = ((const float4*)bias)[t];
  float4 o; o.x = r.x + b.x; o.y = r.y + b.y; o.z = r.z + b.z; o.w = r.w + b.w;
#pragma unroll
  for (int z = 0; z < NS; ++z) {
    const half4 p = ((const half4*)(P + (size_t)z * Mrows * Dm))[idx];
    o.x += (float)p[0]; o.y += (float)p[1]; o.z += (float)p[2]; o.w += (float)p[3];
  }
  ((float4*)x1)[idx] = o;
  float s  = o.x + o.y + o.z + o.w;
  float ss = o.x * o.x + o.y * o.y + o.z * o.z + o.w * o.w;
#pragma unroll
  for (int m = 32; m >= 1; m >>= 1) { s += __shfl_xor(s, m); ss += __shfl_xor(ss, m); }
  __shared__ float red[8];
  if ((t & 63) == 0) { red[t >> 6] = s; red[4 + (t >> 6)] = ss; }
  __syncthreads();
  const float S  = red[0] + red[1] + red[2] + red[3];
  const float SS = red[4] + red[5] + red[6] + red[7];
  const float mean = S * (1.0f / Dm);
  const float inv  = rsqrtf(SS * (1.0f / Dm) - mean * mean + 1e-5f);
  const float4 gg = ((const float4*)g)[t];
  const float4 bv = ((const float4*)bb)[t];
  half4 oh;
  oh[0] = (f16)(((o.x - mean) * inv) * gg.x + bv.x);
  oh[1] = (f16)(((o.y - mean) * inv) * gg.y + bv.y);
  oh[2] = (f16)(((o.z - mean) * inv) * gg.z + bv.z);
  oh[3] = (f16)(((o.w - mean) * inv) * gg.w + bv.w);
  ((half4*)h)[idx] = oh;
}

// plain split-K reduce: out = resid + bias + sum_z P[z]; 16B/lane partial reads (G13)
template <int NS>
__global__ __launch_bounds__(256) void reduceK(const f16* __restrict__ P,
                                               const float* __restrict__ resid,
                                               const float* __restrict__ bias,
                                               float* __restrict__ out) {
  const int t = blockIdx.x * 256 + threadIdx.x;   // 8-f32 group index
  const int col8 = t & (Dm / 8 - 1);
  const float4 r0 = ((const float4*)resid)[2 * t];
  const float4 r1 = ((const float4*)resid)[2 * t + 1];
  const float4 b0 = ((const float4*)bias)[2 * col8];
  const float4 b1 = ((const float4*)bias)[2 * col8 + 1];
  float4 o0, o1;
  o0.x = r0.x + b0.x; o0.y = r0.y + b0.y; o0.z = r0.z + b0.z; o0.w = r0.w + b0.w;
  o1.x = r1.x + b1.x; o1.y = r1.y + b1.y; o1.z = r1.z + b1.z; o1.w = r1.w + b1.w;
#pragma unroll
  for (int z = 0; z < NS; ++z) {
    const half8 p = ((const half8*)(P + (size_t)z * Mrows * Dm))[t];
    o0.x += (float)p[0]; o0.y += (float)p[1]; o0.z += (float)p[2]; o0.w += (float)p[3];
    o1.x += (float)p[4]; o1.y += (float)p[5]; o1.z += (float)p[6]; o1.w += (float)p[7];
  }
  ((float4*)out)[2 * t]     = o0;
  ((float4*)out)[2 * t + 1] = o1;
}

// ---------------------------------------------------------------- GEMM 128x128, BK=64 (f16 MFMA)
// EPI 2: gelu(C+bias)->f16.  EPI 3: C->f16.  EPI 5: f16 partial slab (split-K,
// flat grid, z in low bits).  EPI 2/3: chunked-XCD bx mapping (R4: FFN1 55->45 us,
// B-slab per XCD <=1 MB L2-resident).
template <int EPI, int LNZ>
__global__ __launch_bounds__(256, 4) void gemm_f16(const f16* __restrict__ A,
                                                   const f16* __restrict__ Bt,
                                                   int M, int N, int K, int kLen,
                                                   const float* __restrict__ bias,
                                                   f16* __restrict__ Ch) {
  constexpr int NZ = 1 << LNZ;
  __shared__ f16 As[128 * 64];   // 16 KB
  __shared__ f16 Bs[128 * 64];   // 16 KB
  const int tid = threadIdx.x;
  int bx, by, bz;
  if (EPI == 5) {
    const int lin = blockIdx.x;
    bz = lin & (NZ - 1);
    bx = (lin >> LNZ) & 7;        // N/128 == 8 for these GEMMs
    by = lin >> (LNZ + 3);
  } else {
    const int nbx = N >> 7, chunk = nbx >> 3;
    const int xcd = blockIdx.x & 7, idx = blockIdx.x >> 3;
    bx = xcd * chunk + idx % chunk;
    by = idx / chunk;
    bz = 0;
  }
  const int m0 = by * 128, n0 = bx * 128;
  const int kOff = bz * kLen;
  const int w = tid >> 6, l = tid & 63;
  const int wr = (w >> 1) * 64, wc = (w & 1) * 64;
  const int c = l & 15, qq = l >> 4;
  const int cx = c & 7;            // swizzle key for fragment reads
  const int srow = tid >> 3;       // 0..31 (staging row within 32-row group)
  const int scol = ((tid & 7) ^ (srow & 7)) * 8;  // swizzled global col (f16)

  floatx4 acc[4][4] = {};

  const f16* Ab = A + (size_t)(m0 + srow) * K + kOff + scol;
  const f16* Bb = Bt + (size_t)(n0 + srow) * K + kOff + scol;

  for (int k0 = 0; k0 < kLen; k0 += 64) {
    __syncthreads();
#pragma unroll
    for (int i = 0; i < 4; ++i) {
      ASYNC_COPY16(Ab + k0 + (size_t)(i * 32) * K, As + i * 2048 + w * 512);
      ASYNC_COPY16(Bb + k0 + (size_t)(i * 32) * K, Bs + i * 2048 + w * 512);
    }
    __syncthreads();
    half8 af[4][2], bfr[4][2];
#pragma unroll
    for (int t = 0; t < 4; ++t) {
      const int ra = (wr + t * 16 + c) * 64;
      af[t][0] = *(const half8*)&As[ra + ((qq ^ cx) * 8)];
      af[t][1] = *(const half8*)&As[ra + (((4 + qq) ^ cx) * 8)];
      const int rb = (wc + t * 16 + c) * 64;
      bfr[t][0] = *(const half8*)&Bs[rb + ((qq ^ cx) * 8)];
      bfr[t][1] = *(const half8*)&Bs[rb + (((4 + qq) ^ cx) * 8)];
    }
#pragma unroll
    for (int ti = 0; ti < 4; ++ti)
#pragma unroll
      for (int tj = 0; tj < 4; ++tj) {
        acc[ti][tj] = __builtin_amdgcn_mfma_f32_16x16x32_f16(af[ti][0], bfr[tj][0], acc[ti][tj], 0, 0, 0);
        acc[ti][tj] = __builtin_amdgcn_mfma_f32_16x16x32_f16(af[ti][1], bfr[tj][1], acc[ti][tj], 0, 0, 0);
      }
  }

  f16* Cw = (EPI == 5) ? (Ch + (size_t)bz * M * N) : Ch;
#pragma unroll
  for (int ti = 0; ti < 4; ++ti)
#pragma unroll
    for (int tj = 0; tj < 4; ++tj)
#pragma unroll
      for (int r = 0; r < 4; ++r) {
        const int row = m0 + wr + ti * 16 + qq * 4 + r;
        const int col = n0 + wc + tj * 16 + c;
        const size_t idx = (size_t)row * N + col;
        float v = acc[ti][tj][r];
        if (EPI == 2) {
          Cw[idx] = (f16)gelu_f(v + bias[col]);
        } else {
          Cw[idx] = (f16)v;
        }
      }
}

// ---------------------------------------------------------------- fused attention
// lin in [0,1024): windowed MFMA blocks. For qt>2 the j==0 global column is no
// longer a full 64-key chunk iteration (staging + 2 barriers + 16 MFMAs for ONE
// allowed column); it's folded in as a scalar rank-1 online-softmax step using
// k0/v0 staged once. Avg chunk count 3.8 -> 2.9.
// lin in [1024,1536): global-row T-1 partials (split-j, 512-way block-parallel).
__global__ __launch_bounds__(256, 4) void attn_fused(const f16* __restrict__ qkv,
                                                     f16* __restrict__ ao,
                                                     float* __restrict__ part) {
  __shared__ f16 qs[64 * PAD];   // [i][d]
  __shared__ f16 ks[64 * PAD];   // [j][d]
  __shared__ f16 vts[64 * PAD];  // [d][j]  (transposed)
  __shared__ f16 ps[64 * PAD];   // [i][j]  wave-private row slices
  __shared__ float k0f[64];      // K row 0 (f32)
  __shared__ float v0f[64];      // V row 0 (f32)
  const int lin = blockIdx.x;
  const int tid = threadIdx.x;

  if (lin >= 1024) {
    // ---------------- global row i = T-1 (split-j), LDS overlaid on attn tiles
    const int r_ = lin - 1024;
    const int bh = r_ & 31, sp = r_ >> 5;
    const int b = bh >> 4, hh = bh & 15;
    const size_t base = ((size_t)b * Tseq) * QS + hh * HDim;
    const int j0 = sp * (Tseq / NSPLIT);   // 128 keys per split
    float* qsh  = (float*)qs;              // 64 floats
    float* psf  = (float*)ks;              // 128 floats
    float* red  = (float*)vts;             // 4
    float* red2 = red + 4;                 // 4
    float (*oaccp)[64] = (float(*)[64])ps; // 4 x 64 floats
    if (tid < 64) qsh[tid] = (float)qkv[base + (size_t)(Tseq - 1) * QS + tid] * 0.125f;
    __syncthreads();
    float sv = -INFINITY;
    if (tid < 128) {
      const f16* kr = qkv + base + 1024 + (size_t)(j0 + tid) * QS;
      float a0 = 0.f;
#pragma unroll
      for (int d8 = 0; d8 < 8; ++d8) {
        const half8 kv = *(const half8*)(kr + d8 * 8);
#pragma unroll
        for (int e = 0; e < 8; ++e) a0 = fmaf((float)kv[e], qsh[d8 * 8 + e], a0);
      }
      sv = a0;  // row T-1: all j <= T-1 allowed
    }
    float mx = sv;
#pragma unroll
    for (int mm = 32; mm >= 1; mm >>= 1) mx = fmaxf(mx, __shfl_xor(mx, mm));
    if ((tid & 63) == 0) red[tid >> 6] = mx;
    __syncthreads();
    const float M = fmaxf(red[0], red[1]);  // waves 2,3 hold -inf
    float p = 0.f;
    if (tid < 128) { p = __expf(sv - M); psf[tid] = p; }
    float sum = p;
#pragma unroll
    for (int mm = 32; mm >= 1; mm >>= 1) sum += __shfl_xor(sum, mm);
    if ((tid & 63) == 0) red2[tid >> 6] = sum;
    __syncthreads();
    const float L = red2[0] + red2[1];
    const int d = tid & 63, pt = tid >> 6;
    const f16* vb = qkv + base + 2048 + d;
    float acc = 0.f;
    for (int j = pt * 32; j < pt * 32 + 32; ++j)
      acc = fmaf(psf[j], (float)vb[(size_t)(j0 + j) * QS], acc);
    oaccp[pt][d] = acc;
    __syncthreads();
    if (tid < 64) {
      const float o = oaccp[0][tid] + oaccp[1][tid] + oaccp[2][tid] + oaccp[3][tid];
      float* dst = part + ((size_t)bh * NSPLIT + sp) * 66;
      dst[tid] = o;
      if (tid == 0) { dst[64] = M; dst[65] = L; }
    }
    return;
  }

  // ---------------- windowed attention (MFMA)
  const int qt = lin & 31;
  const int byv = lin >> 5;
  const int b = byv >> 4, hh = byv & 15;
  const int q0 = qt * 64;
  const int w = tid >> 6, l = tid & 63;
  const int c = l & 15, qq = l >> 4;
  const int wr = w * 16;
  const size_t base = ((size_t)b * Tseq) * QS + hh * HDim;
  const int rr = tid >> 2, ss = (tid & 3) * 16;

  {
    const f16* src = qkv + base + (size_t)(q0 + rr) * QS + ss;
    *(uint4*)&qs[rr * PAD + ss]     = *(const uint4*)src;
    *(uint4*)&qs[rr * PAD + ss + 8] = *(const uint4*)(src + 8);
    if (tid < 64) {
      k0f[tid] = (float)qkv[base + 1024 + tid];  // K row 0
      v0f[tid] = (float)qkv[base + 2048 + tid];  // V row 0
    }
  }

  float m_run[4], l_run[4];
  floatx4 oacc[4];
#pragma unroll
  for (int r = 0; r < 4; ++r) { m_run[r] = -INFINITY; l_run[r] = 0.f; }
#pragma unroll
  for (int td = 0; td < 4; ++td) oacc[td] = (floatx4){0.f, 0.f, 0.f, 0.f};

  // window chunks only; j==0 handled scalar-style below for qt>2
  int chunks[4]; int nch = 0;
  for (int ch = (qt - 2 > 0 ? qt - 2 : 0); ch <= qt; ++ch) chunks[nch++] = ch;

  for (int ci = 0; ci < nch; ++ci) {
    const int j0 = chunks[ci] * 64;
    __syncthreads();
    {
      const f16* srck = qkv + base + 1024 + (size_t)(j0 + rr) * QS + ss;
      *(uint4*)&ks[rr * PAD + ss]     = *(const uint4*)srck;
      *(uint4*)&ks[rr * PAD + ss + 8] = *(const uint4*)(srck + 8);
      const f16* srcv = qkv + base + 2048 + (size_t)(j0 + rr) * QS + ss;
      uint4 va0 = *(const uint4*)srcv;
      uint4 va1 = *(const uint4*)(srcv + 8);
      const f16* e0 = (const f16*)&va0;
      const f16* e1 = (const f16*)&va1;
#pragma unroll
      for (int i = 0; i < 8; ++i) vts[(ss + i) * PAD + rr] = e0[i];
#pragma unroll
      for (int i = 0; i < 8; ++i) vts[(ss + 8 + i) * PAD + rr] = e1[i];
    }
    __syncthreads();

    const half8 a0 = *(const half8*)&qs[(wr + c) * PAD + qq * 8];
    const half8 a1 = *(const half8*)&qs[(wr + c) * PAD + 32 + qq * 8];
    floatx4 sacc[4];
#pragma unroll
    for (int tj = 0; tj < 4; ++tj) {
      const half8 b0 = *(const half8*)&ks[(tj * 16 + c) * PAD + qq * 8];
      const half8 b1 = *(const half8*)&ks[(tj * 16 + c) * PAD + 32 + qq * 8];
      floatx4 s4 = {0.f, 0.f, 0.f, 0.f};
      s4 = __builtin_amdgcn_mfma_f32_16x16x32_f16(a0, b0, s4, 0, 0, 0);
      s4 = __builtin_amdgcn_mfma_f32_16x16x32_f16(a1, b1, s4, 0, 0, 0);
      sacc[tj] = s4;
    }

#pragma unroll
    for (int r = 0; r < 4; ++r) {
      const int ii = q0 + wr + qq * 4 + r;
      float sv[4];
      float mx = -INFINITY;
#pragma unroll
      for (int tj = 0; tj < 4; ++tj) {
        const int jj = j0 + tj * 16 + c;
        const bool allowed = (jj <= ii) && ((ii - jj) <= 128 || jj == 0);
        sv[tj] = allowed ? sacc[tj][r] * 0.125f : -INFINITY;
        mx = fmaxf(mx, sv[tj]);
      }
#pragma unroll
      for (int mm = 8; mm >= 1; mm >>= 1) mx = fmaxf(mx, __shfl_xor(mx, mm));
      const float mn = fmaxf(m_run[r], mx);
      const float alpha = (mn == -INFINITY) ? 1.f : __expf(m_run[r] - mn);
      float sum = 0.f;
      float p[4];
#pragma unroll
      for (int tj = 0; tj < 4; ++tj) { p[tj] = __expf(sv[tj] - mn); sum += p[tj]; }
#pragma unroll
      for (int mm = 8; mm >= 1; mm >>= 1) sum += __shfl_xor(sum, mm);
      l_run[r] = l_run[r] * alpha + sum;
      m_run[r] = mn;
#pragma unroll
      for (int td = 0; td < 4; ++td) oacc[td][r] *= alpha;
#pragma unroll
      for (int tj = 0; tj < 4; ++tj)
        ps[(wr + qq * 4 + r) * PAD + tj * 16 + c] = (f16)p[tj];
    }

    const half8 p0 = *(const half8*)&ps[(wr + c) * PAD + qq * 8];
    const half8 p1 = *(const half8*)&ps[(wr + c) * PAD + 32 + qq * 8];
#pragma unroll
    for (int td = 0; td < 4; ++td) {
      const half8 b0 = *(const half8*)&vts[(td * 16 + c) * PAD + qq * 8];
      const half8 b1 = *(const half8*)&vts[(td * 16 + c) * PAD + 32 + qq * 8];
      oacc[td] = __builtin_amdgcn_mfma_f32_16x16x32_f16(p0, b0, oacc[td], 0, 0, 0);
      oacc[td] = __builtin_amdgcn_mfma_f32_16x16x32_f16(p1, b1, oacc[td], 0, 0, 0);
    }
  }

  // ---- j==0 global column as a scalar online-softmax step (qt>2 only; for
  // qt<=2 chunk 0 was inside the loop). All rows here satisfy ii>=192>0.
  if (qt > 2) {
    float kk[4], vv[4];
#pragma unroll
    for (int e = 0; e < 4; ++e) kk[e] = k0f[c * 4 + e];
#pragma unroll
    for (int td = 0; td < 4; ++td) vv[td] = v0f[td * 16 + c];
#pragma unroll
    for (int r = 0; r < 4; ++r) {
      const int row = wr + qq * 4 + r;
      float part = 0.f;
#pragma unroll
      for (int e = 0; e < 4; ++e)
        part = fmaf((float)qs[row * PAD + c * 4 + e], kk[e], part);
#pragma unroll
      for (int mm = 8; mm >= 1; mm >>= 1) part += __shfl_xor(part, mm);
      const float s0 = part * 0.125f;
      const float mn = fmaxf(m_run[r], s0);
      const float alpha = __expf(m_run[r] - mn);
      const float p0 = __expf(s0 - mn);
      l_run[r] = l_run[r] * alpha + p0;
      m_run[r] = mn;
#pragma unroll
      for (int td = 0; td < 4; ++td)
        oacc[td][r] = oacc[td][r] * alpha + p0 * vv[td];
    }
  }

#pragma unroll
  for (int td = 0; td < 4; ++td)
#pragma unroll
    for (int r = 0; r < 4; ++r) {
      const int ii = q0 + wr + qq * 4 + r;
      ao[((size_t)(b * Tseq + ii)) * Dm + hh * HDim + td * 16 + c] =
          (f16)(oacc[td][r] / l_run[r]);
    }
}

// Combine NSPLIT partials per (b,h) and write row T-1 of attnF.
__global__ __launch_bounds__(64) void attn_row_comb(const float* __restrict__ part,
                                                    f16* __restrict__ ao) {
  const int bh = blockIdx.x;
  const int b = bh >> 4, hh = bh & 15;
  const int tid = threadIdx.x;
  const float* pp = part + (size_t)bh * NSPLIT * 66;
  float M = -INFINITY;
#pragma unroll
  for (int s = 0; s < NSPLIT; ++s) M = fmaxf(M, pp[s * 66 + 64]);
  float L = 0.f, o = 0.f;
#pragma unroll
  for (int s = 0; s < NSPLIT; ++s) {
    const float wgt = __expf(pp[s * 66 + 64] - M);
    L += pp[s * 66 + 65] * wgt;
    o += pp[s * 66 + tid] * wgt;
  }
  ao[((size_t)(b * Tseq + Tseq - 1)) * Dm + hh * HDim + tid] = (f16)(o / L);
}

// ---------------------------------------------------------------- launch
extern "C" void kernel_launch(void* const* d_in, const int* in_sizes, int n_in,
                              void* d_out, int out_size, void* d_ws, size_t ws_size,
                              hipStream_t stream) {
  (void)in_sizes; (void)n_in; (void)out_size; (void)ws_size;
  const float* x    = (const float*)d_in[0];
  const float* ln1g = (const float*)d_in[1];
  const float* ln1b = (const float*)d_in[2];
  const float* ln2g = (const float*)d_in[3];
  const float* ln2b = (const float*)d_in[4];
  const float* Wq   = (const float*)d_in[5];
  const float* Wk   = (const float*)d_in[6];
  const float* Wv   = (const float*)d_in[7];
  const float* Wo   = (const float*)d_in[8];
  const float* bo   = (const float*)d_in[9];
  const float* W1   = (const float*)d_in[10];
  const float* b1   = (const float*)d_in[11];
  const float* W2   = (const float*)d_in[12];
  const float* b2   = (const float*)d_in[13];
  float* out = (float*)d_out;

  char* w0 = (char*)d_ws;
  size_t off = 0;
  auto take = [&](size_t bytes) -> char* {
    char* p = w0 + off;
    off += (bytes + 255) & ~(size_t)255;
    return p;
  };
  f16*   WqkvT = (f16*)take((size_t)3 * Dm * Dm * 2);  // Wq^T | Wk^T | Wv^T stacked
  f16*   WoT   = (f16*)take((size_t)Dm * Dm * 2);
  f16*   W1T   = (f16*)take((size_t)Dm * 4 * Dm * 2);
  f16*   W2T   = (f16*)take((size_t)Dm * 4 * Dm * 2);
  f16*   hF    = (f16*)take((size_t)Mrows * Dm * 2);
  f16*   qkvh  = (f16*)take((size_t)Mrows * QS * 2);   // 24 MiB
  f16*   attnF = (f16*)take((size_t)Mrows * Dm * 2);   // 8 MiB, contiguous after qkvh
  float* x1    = (float*)take((size_t)Mrows * Dm * 4);
  f16*   h2F   = (f16*)take((size_t)Mrows * Dm * 2);
  f16*   pbuf  = (f16*)take((size_t)4 * Mrows * Dm * 2);  // split-K f16 partials (32 MB)
  float* rowp  = (float*)take((size_t)32 * NSPLIT * 66 * 4);  // global-row partials
  f16*   ffn1F = qkvh;  // 4096x4096 f16 = 32 MiB == qkvh(24) + attnF(8) span

  const dim3 blk(256);

  // prep: 6 transposes + LN1 in one launch (16384 blocks)
  prep<<<dim3(16384), blk, 0, stream>>>(Wq, Wk, Wv, Wo, W1, W2, x, ln1g, ln1b,
                                        WqkvT, WoT, W1T, W2T, hF);

  // fused QKV: (4096x1024)@(1024x3072) -> qkvh; 768 blocks, chunked-XCD bx
  gemm_f16<3, 0><<<dim3(768), blk, 0, stream>>>(
      hF, WqkvT, Mrows, QS, Dm, Dm, nullptr, qkvh);

  // attention: windowed (1024) + global-row split-j partials (512), one launch
  attn_fused<<<dim3(1536), blk, 0, stream>>>(qkvh, attnF, rowp);
  attn_row_comb<<<dim3(2 * NHd), dim3(64), 0, stream>>>(rowp, attnF);

  // Wo: split-K2 f16 partials, flat grid with z in low bits (512 blocks)
  gemm_f16<5, 1><<<dim3(512), blk, 0, stream>>>(
      attnF, WoT, Mrows, Dm, Dm, Dm / 2, nullptr, pbuf);
  reduce_ln<2><<<Mrows, blk, 0, stream>>>(pbuf, x, bo, ln2g, ln2b, x1, h2F);

  // FFN1: N=4096, 1024 blocks, chunked-XCD bx, fast-GELU epilogue
  gemm_f16<2, 0><<<dim3(1024), blk, 0, stream>>>(
      h2F, W1T, Mrows, 4 * Dm, Dm, Dm, b1, ffn1F);

  // W2: split-K4 f16 partials, flat grid (1024 blocks), then out = x1 + b2 + sum(P)
  gemm_f16<5, 2><<<dim3(1024), blk, 0, stream>>>(
      ffn1F, W2T, Mrows, Dm, 4 * Dm, Dm, nullptr, pbuf);
  reduceK<4><<<Mrows * Dm / (256 * 8), blk, 0, stream>>>(pbuf, x1, b2, out);
}

// Round 8
// 295.511 us; speedup vs baseline: 1.2695x; 1.0324x over previous
//
#include <hip/hip_runtime.h>
#include <cmath>

#define Tseq 2048
#define Dm   1024
#define NHd  16
#define HDim 64
#define Mrows 4096   // B*T = 2*2048
#define QS   3072    // packed QKV row stride (f16 elems)
#define PAD  72      // LDS row stride (f16) for attention tiles
#define NSPLIT 16    // j-splits for the global row (i = T-1)

typedef _Float16 f16;
typedef _Float16 half8 __attribute__((ext_vector_type(8)));
typedef _Float16 half4 __attribute__((ext_vector_type(4)));
typedef float    floatx4 __attribute__((ext_vector_type(4)));

#define ASYNC_COPY16(g, l)                                                       \
  __builtin_amdgcn_global_load_lds((const __attribute__((address_space(1))) void*)(g), \
                                   (__attribute__((address_space(3))) void*)(l), 16, 0, 0)

// tanh-form GELU, one __expf. |err vs exact erf-GELU| <= ~3e-4.
__device__ __forceinline__ float gelu_f(float v) {
  const float u = 0.7978845608028654f * (v + 0.044715f * v * v * v);
  const float e = __expf(2.0f * u);
  return 0.5f * v * (2.0f - 2.0f / (e + 1.0f));
}

// ---------------------------------------------------------------- fused prep
// One launch: 6 weight transposes (f32 -> f16^T) + LN1 (x -> hF).
__device__ __forceinline__ void transp_body(const float* __restrict__ W,
                                            f16* __restrict__ Wt, int K, int N,
                                            int bx, int by, float (*tile)[33]) {
  const int n0 = bx * 32, k0 = by * 32;
  const int tx = threadIdx.x & 31, ty = threadIdx.x >> 5;
#pragma unroll
  for (int i = 0; i < 32; i += 8)
    tile[ty + i][tx] = W[(size_t)(k0 + ty + i) * N + n0 + tx];
  __syncthreads();
#pragma unroll
  for (int i = 0; i < 32; i += 8)
    Wt[(size_t)(n0 + ty + i) * K + k0 + tx] = (f16)tile[tx][ty + i];
}

__global__ __launch_bounds__(256) void prep(const float* __restrict__ Wq,
                                            const float* __restrict__ Wk,
                                            const float* __restrict__ Wv,
                                            const float* __restrict__ Wo,
                                            const float* __restrict__ W1,
                                            const float* __restrict__ W2,
                                            const float* __restrict__ x,
                                            const float* __restrict__ g,
                                            const float* __restrict__ bb,
                                            f16* __restrict__ WqkvT,
                                            f16* __restrict__ WoT,
                                            f16* __restrict__ W1T,
                                            f16* __restrict__ W2T,
                                            f16* __restrict__ hF) {
  __shared__ float tile[32][33];
  __shared__ float red[8];
  const int lin = blockIdx.x;
  if (lin < 4096) {
    const int wsel = lin >> 10, t = lin & 1023;
    const float* W = (wsel == 0) ? Wq : (wsel == 1) ? Wk : (wsel == 2) ? Wv : Wo;
    f16* dst = (wsel < 3) ? (WqkvT + (size_t)wsel * Dm * Dm) : WoT;
    transp_body(W, dst, Dm, Dm, t & 31, t >> 5, tile);
    return;
  }
  if (lin < 8192) {
    const int t = lin - 4096;
    transp_body(W1, W1T, Dm, 4 * Dm, t & 127, t >> 7, tile);
    return;
  }
  if (lin < 12288) {
    const int t = lin - 8192;
    transp_body(W2, W2T, 4 * Dm, Dm, t & 31, t >> 5, tile);
    return;
  }
  // ---- LN1 row
  const int row = lin - 12288, t = threadIdx.x;
  const float4 v = ((const float4*)(x + (size_t)row * Dm))[t];
  float s  = v.x + v.y + v.z + v.w;
  float ss = v.x * v.x + v.y * v.y + v.z * v.z + v.w * v.w;
#pragma unroll
  for (int m = 32; m >= 1; m >>= 1) { s += __shfl_xor(s, m); ss += __shfl_xor(ss, m); }
  if ((t & 63) == 0) { red[t >> 6] = s; red[4 + (t >> 6)] = ss; }
  __syncthreads();
  const float S  = red[0] + red[1] + red[2] + red[3];
  const float SS = red[4] + red[5] + red[6] + red[7];
  const float mean = S * (1.0f / Dm);
  const float inv  = rsqrtf(SS * (1.0f / Dm) - mean * mean + 1e-5f);
  const float4 gg = ((const float4*)g)[t];
  const float4 bv = ((const float4*)bb)[t];
  half4 o;
  o.x = (f16)(((v.x - mean) * inv) * gg.x + bv.x);
  o.y = (f16)(((v.y - mean) * inv) * gg.y + bv.y);
  o.z = (f16)(((v.z - mean) * inv) * gg.z + bv.z);
  o.w = (f16)(((v.w - mean) * inv) * gg.w + bv.w);
  *((half4*)(hF + (size_t)row * Dm) + t) = o;
}

// ---------------------------------------------------------------- split-K reduce (+ fused LN)
template <int NS>
__global__ __launch_bounds__(256) void reduce_ln(const f16* __restrict__ P,
                                                 const float* __restrict__ resid,
                                                 const float* __restrict__ bias,
                                                 const float* __restrict__ g,
                                                 const float* __restrict__ bb,
                                                 float* __restrict__ x1,
                                                 f16* __restrict__ h) {
  const int row = blockIdx.x, t = threadIdx.x;
  const size_t idx = (size_t)row * (Dm / 4) + t;
  const float4 r = ((const float4*)resid)[idx];
  const float4 b = ((const float4*)bias)[t];
  float4 o; o.x = r.x + b.x; o.y = r.y + b.y; o.z = r.z + b.z; o.w = r.w + b.w;
#pragma unroll
  for (int z = 0; z < NS; ++z) {
    const half4 p = ((const half4*)(P + (size_t)z * Mrows * Dm))[idx];
    o.x += (float)p[0]; o.y += (float)p[1]; o.z += (float)p[2]; o.w += (float)p[3];
  }
  ((float4*)x1)[idx] = o;
  float s  = o.x + o.y + o.z + o.w;
  float ss = o.x * o.x + o.y * o.y + o.z * o.z + o.w * o.w;
#pragma unroll
  for (int m = 32; m >= 1; m >>= 1) { s += __shfl_xor(s, m); ss += __shfl_xor(ss, m); }
  __shared__ float red[8];
  if ((t & 63) == 0) { red[t >> 6] = s; red[4 + (t >> 6)] = ss; }
  __syncthreads();
  const float S  = red[0] + red[1] + red[2] + red[3];
  const float SS = red[4] + red[5] + red[6] + red[7];
  const float mean = S * (1.0f / Dm);
  const float inv  = rsqrtf(SS * (1.0f / Dm) - mean * mean + 1e-5f);
  const float4 gg = ((const float4*)g)[t];
  const float4 bv = ((const float4*)bb)[t];
  half4 oh;
  oh[0] = (f16)(((o.x - mean) * inv) * gg.x + bv.x);
  oh[1] = (f16)(((o.y - mean) * inv) * gg.y + bv.y);
  oh[2] = (f16)(((o.z - mean) * inv) * gg.z + bv.z);
  oh[3] = (f16)(((o.w - mean) * inv) * gg.w + bv.w);
  ((half4*)h)[idx] = oh;
}

// plain split-K reduce: out = resid + bias + sum_z P[z]; 16B/lane partial reads (G13)
template <int NS>
__global__ __launch_bounds__(256) void reduceK(const f16* __restrict__ P,
                                               const float* __restrict__ resid,
                                               const float* __restrict__ bias,
                                               float* __restrict__ out) {
  const int t = blockIdx.x * 256 + threadIdx.x;   // 8-f32 group index
  const int col8 = t & (Dm / 8 - 1);
  const float4 r0 = ((const float4*)resid)[2 * t];
  const float4 r1 = ((const float4*)resid)[2 * t + 1];
  const float4 b0 = ((const float4*)bias)[2 * col8];
  const float4 b1 = ((const float4*)bias)[2 * col8 + 1];
  float4 o0, o1;
  o0.x = r0.x + b0.x; o0.y = r0.y + b0.y; o0.z = r0.z + b0.z; o0.w = r0.w + b0.w;
  o1.x = r1.x + b1.x; o1.y = r1.y + b1.y; o1.z = r1.z + b1.z; o1.w = r1.w + b1.w;
#pragma unroll
  for (int z = 0; z < NS; ++z) {
    const half8 p = ((const half8*)(P + (size_t)z * Mrows * Dm))[t];
    o0.x += (float)p[0]; o0.y += (float)p[1]; o0.z += (float)p[2]; o0.w += (float)p[3];
    o1.x += (float)p[4]; o1.y += (float)p[5]; o1.z += (float)p[6]; o1.w += (float)p[7];
  }
  ((float4*)out)[2 * t]     = o0;
  ((float4*)out)[2 * t + 1] = o1;
}

// ---------------------------------------------------------------- GEMM 128x128, BK=64 (f16 MFMA)
// EPI 2: gelu(C+bias)->f16.  EPI 3: C->f16.  EPI 5: f16 partial slab (split-K,
// flat grid, z in low bits).  EPI 2/3: chunked-XCD bx mapping (R4: FFN1 55->45 us,
// B-slab per XCD <=1 MB L2-resident).
template <int EPI, int LNZ>
__global__ __launch_bounds__(256, 4) void gemm_f16(const f16* __restrict__ A,
                                                   const f16* __restrict__ Bt,
                                                   int M, int N, int K, int kLen,
                                                   const float* __restrict__ bias,
                                                   f16* __restrict__ Ch) {
  constexpr int NZ = 1 << LNZ;
  __shared__ f16 As[128 * 64];   // 16 KB
  __shared__ f16 Bs[128 * 64];   // 16 KB
  const int tid = threadIdx.x;
  int bx, by, bz;
  if (EPI == 5) {
    const int lin = blockIdx.x;
    bz = lin & (NZ - 1);
    bx = (lin >> LNZ) & 7;        // N/128 == 8 for these GEMMs
    by = lin >> (LNZ + 3);
  } else {
    const int nbx = N >> 7, chunk = nbx >> 3;
    const int xcd = blockIdx.x & 7, idx = blockIdx.x >> 3;
    bx = xcd * chunk + idx % chunk;
    by = idx / chunk;
    bz = 0;
  }
  const int m0 = by * 128, n0 = bx * 128;
  const int kOff = bz * kLen;
  const int w = tid >> 6, l = tid & 63;
  const int wr = (w >> 1) * 64, wc = (w & 1) * 64;
  const int c = l & 15, qq = l >> 4;
  const int cx = c & 7;            // swizzle key for fragment reads
  const int srow = tid >> 3;       // 0..31 (staging row within 32-row group)
  const int scol = ((tid & 7) ^ (srow & 7)) * 8;  // swizzled global col (f16)

  floatx4 acc[4][4] = {};

  const f16* Ab = A + (size_t)(m0 + srow) * K + kOff + scol;
  const f16* Bb = Bt + (size_t)(n0 + srow) * K + kOff + scol;

  for (int k0 = 0; k0 < kLen; k0 += 64) {
    __syncthreads();
#pragma unroll
    for (int i = 0; i < 4; ++i) {
      ASYNC_COPY16(Ab + k0 + (size_t)(i * 32) * K, As + i * 2048 + w * 512);
      ASYNC_COPY16(Bb + k0 + (size_t)(i * 32) * K, Bs + i * 2048 + w * 512);
    }
    __syncthreads();
    half8 af[4][2], bfr[4][2];
#pragma unroll
    for (int t = 0; t < 4; ++t) {
      const int ra = (wr + t * 16 + c) * 64;
      af[t][0] = *(const half8*)&As[ra + ((qq ^ cx) * 8)];
      af[t][1] = *(const half8*)&As[ra + (((4 + qq) ^ cx) * 8)];
      const int rb = (wc + t * 16 + c) * 64;
      bfr[t][0] = *(const half8*)&Bs[rb + ((qq ^ cx) * 8)];
      bfr[t][1] = *(const half8*)&Bs[rb + (((4 + qq) ^ cx) * 8)];
    }
#pragma unroll
    for (int ti = 0; ti < 4; ++ti)
#pragma unroll
      for (int tj = 0; tj < 4; ++tj) {
        acc[ti][tj] = __builtin_amdgcn_mfma_f32_16x16x32_f16(af[ti][0], bfr[tj][0], acc[ti][tj], 0, 0, 0);
        acc[ti][tj] = __builtin_amdgcn_mfma_f32_16x16x32_f16(af[ti][1], bfr[tj][1], acc[ti][tj], 0, 0, 0);
      }
  }

  f16* Cw = (EPI == 5) ? (Ch + (size_t)bz * M * N) : Ch;
#pragma unroll
  for (int ti = 0; ti < 4; ++ti)
#pragma unroll
    for (int tj = 0; tj < 4; ++tj)
#pragma unroll
      for (int r = 0; r < 4; ++r) {
        const int row = m0 + wr + ti * 16 + qq * 4 + r;
        const int col = n0 + wc + tj * 16 + c;
        const size_t idx = (size_t)row * N + col;
        float v = acc[ti][tj][r];
        if (EPI == 2) {
          Cw[idx] = (f16)gelu_f(v + bias[col]);
        } else {
          Cw[idx] = (f16)v;
        }
      }
}

// ---------------------------------------------------------------- fused attention
// lin in [0,1024): windowed MFMA blocks (chunk-0 global column folded scalar,
// R7). LDS XOR swizzle (T2/G4) on vts and ps: vts scalar writes previously hit
// only 8 banks (4d term collapses mod 32; 4-8-way), ps stores 4-way via the
// 16*qq alias. Swizzle: group-of-8 XOR -- vts (d,j) -> d*PAD + ((j>>3 ^ d>>3)&7)*8
// + (j&7); ps (row,col) -> row*PAD + ((col>>3 ^ (row>>1))&7)*8 + (col&7). Reads
// apply the identical key; bijective per row => math unchanged.
// lin in [1024,1536): global-row T-1 partials (split-j, 512-way block-parallel).
__global__ __launch_bounds__(256, 4) void attn_fused(const f16* __restrict__ qkv,
                                                     f16* __restrict__ ao,
                                                     float* __restrict__ part) {
  __shared__ f16 qs[64 * PAD];   // [i][d]
  __shared__ f16 ks[64 * PAD];   // [j][d]
  __shared__ f16 vts[64 * PAD];  // [d][j]  (transposed, XOR-swizzled)
  __shared__ f16 ps[64 * PAD];   // [i][j]  (XOR-swizzled)
  __shared__ float k0f[64];      // K row 0 (f32)
  __shared__ float v0f[64];      // V row 0 (f32)
  const int lin = blockIdx.x;
  const int tid = threadIdx.x;

  if (lin >= 1024) {
    // ---------------- global row i = T-1 (split-j), LDS overlaid on attn tiles
    const int r_ = lin - 1024;
    const int bh = r_ & 31, sp = r_ >> 5;
    const int b = bh >> 4, hh = bh & 15;
    const size_t base = ((size_t)b * Tseq) * QS + hh * HDim;
    const int j0 = sp * (Tseq / NSPLIT);   // 128 keys per split
    float* qsh  = (float*)qs;              // 64 floats
    float* psf  = (float*)ks;              // 128 floats
    float* red  = (float*)vts;             // 4
    float* red2 = red + 4;                 // 4
    float (*oaccp)[64] = (float(*)[64])ps; // 4 x 64 floats
    if (tid < 64) qsh[tid] = (float)qkv[base + (size_t)(Tseq - 1) * QS + tid] * 0.125f;
    __syncthreads();
    float sv = -INFINITY;
    if (tid < 128) {
      const f16* kr = qkv + base + 1024 + (size_t)(j0 + tid) * QS;
      float a0 = 0.f;
#pragma unroll
      for (int d8 = 0; d8 < 8; ++d8) {
        const half8 kv = *(const half8*)(kr + d8 * 8);
#pragma unroll
        for (int e = 0; e < 8; ++e) a0 = fmaf((float)kv[e], qsh[d8 * 8 + e], a0);
      }
      sv = a0;  // row T-1: all j <= T-1 allowed
    }
    float mx = sv;
#pragma unroll
    for (int mm = 32; mm >= 1; mm >>= 1) mx = fmaxf(mx, __shfl_xor(mx, mm));
    if ((tid & 63) == 0) red[tid >> 6] = mx;
    __syncthreads();
    const float M = fmaxf(red[0], red[1]);  // waves 2,3 hold -inf
    float p = 0.f;
    if (tid < 128) { p = __expf(sv - M); psf[tid] = p; }
    float sum = p;
#pragma unroll
    for (int mm = 32; mm >= 1; mm >>= 1) sum += __shfl_xor(sum, mm);
    if ((tid & 63) == 0) red2[tid >> 6] = sum;
    __syncthreads();
    const float L = red2[0] + red2[1];
    const int d = tid & 63, pt = tid >> 6;
    const f16* vb = qkv + base + 2048 + d;
    float acc = 0.f;
    for (int j = pt * 32; j < pt * 32 + 32; ++j)
      acc = fmaf(psf[j], (float)vb[(size_t)(j0 + j) * QS], acc);
    oaccp[pt][d] = acc;
    __syncthreads();
    if (tid < 64) {
      const float o = oaccp[0][tid] + oaccp[1][tid] + oaccp[2][tid] + oaccp[3][tid];
      float* dst = part + ((size_t)bh * NSPLIT + sp) * 66;
      dst[tid] = o;
      if (tid == 0) { dst[64] = M; dst[65] = L; }
    }
    return;
  }

  // ---------------- windowed attention (MFMA)
  const int qt = lin & 31;
  const int byv = lin >> 5;
  const int b = byv >> 4, hh = byv & 15;
  const int q0 = qt * 64;
  const int w = tid >> 6, l = tid & 63;
  const int c = l & 15, qq = l >> 4;
  const int wr = w * 16;
  const size_t base = ((size_t)b * Tseq) * QS + hh * HDim;
  const int rr = tid >> 2, ss = (tid & 3) * 16;

  {
    const f16* src = qkv + base + (size_t)(q0 + rr) * QS + ss;
    *(uint4*)&qs[rr * PAD + ss]     = *(const uint4*)src;
    *(uint4*)&qs[rr * PAD + ss + 8] = *(const uint4*)(src + 8);
    if (tid < 64) {
      k0f[tid] = (float)qkv[base + 1024 + tid];  // K row 0
      v0f[tid] = (float)qkv[base + 2048 + tid];  // V row 0
    }
  }

  float m_run[4], l_run[4];
  floatx4 oacc[4];
#pragma unroll
  for (int r = 0; r < 4; ++r) { m_run[r] = -INFINITY; l_run[r] = 0.f; }
#pragma unroll
  for (int td = 0; td < 4; ++td) oacc[td] = (floatx4){0.f, 0.f, 0.f, 0.f};

  // window chunks only; j==0 handled scalar-style below for qt>2
  int chunks[4]; int nch = 0;
  for (int ch = (qt - 2 > 0 ? qt - 2 : 0); ch <= qt; ++ch) chunks[nch++] = ch;

  for (int ci = 0; ci < nch; ++ci) {
    const int j0 = chunks[ci] * 64;
    __syncthreads();
    {
      const f16* srck = qkv + base + 1024 + (size_t)(j0 + rr) * QS + ss;
      *(uint4*)&ks[rr * PAD + ss]     = *(const uint4*)srck;
      *(uint4*)&ks[rr * PAD + ss + 8] = *(const uint4*)(srck + 8);
      const f16* srcv = qkv + base + 2048 + (size_t)(j0 + rr) * QS + ss;
      uint4 va0 = *(const uint4*)srcv;
      uint4 va1 = *(const uint4*)(srcv + 8);
      const f16* e0 = (const f16*)&va0;
      const f16* e1 = (const f16*)&va1;
      const int jg = rr >> 3, jo = rr & 7;   // j group / offset
#pragma unroll
      for (int i = 0; i < 8; ++i) {
        const int d = ss + i;
        vts[d * PAD + (((jg ^ (d >> 3)) & 7) << 3) + jo] = e0[i];
      }
#pragma unroll
      for (int i = 0; i < 8; ++i) {
        const int d = ss + 8 + i;
        vts[d * PAD + (((jg ^ (d >> 3)) & 7) << 3) + jo] = e1[i];
      }
    }
    __syncthreads();

    const half8 a0 = *(const half8*)&qs[(wr + c) * PAD + qq * 8];
    const half8 a1 = *(const half8*)&qs[(wr + c) * PAD + 32 + qq * 8];
    floatx4 sacc[4];
#pragma unroll
    for (int tj = 0; tj < 4; ++tj) {
      const half8 b0 = *(const half8*)&ks[(tj * 16 + c) * PAD + qq * 8];
      const half8 b1 = *(const half8*)&ks[(tj * 16 + c) * PAD + 32 + qq * 8];
      floatx4 s4 = {0.f, 0.f, 0.f, 0.f};
      s4 = __builtin_amdgcn_mfma_f32_16x16x32_f16(a0, b0, s4, 0, 0, 0);
      s4 = __builtin_amdgcn_mfma_f32_16x16x32_f16(a1, b1, s4, 0, 0, 0);
      sacc[tj] = s4;
    }

#pragma unroll
    for (int r = 0; r < 4; ++r) {
      const int ii = q0 + wr + qq * 4 + r;
      float sv[4];
      float mx = -INFINITY;
#pragma unroll
      for (int tj = 0; tj < 4; ++tj) {
        const int jj = j0 + tj * 16 + c;
        const bool allowed = (jj <= ii) && ((ii - jj) <= 128 || jj == 0);
        sv[tj] = allowed ? sacc[tj][r] * 0.125f : -INFINITY;
        mx = fmaxf(mx, sv[tj]);
      }
#pragma unroll
      for (int mm = 8; mm >= 1; mm >>= 1) mx = fmaxf(mx, __shfl_xor(mx, mm));
      const float mn = fmaxf(m_run[r], mx);
      const float alpha = (mn == -INFINITY) ? 1.f : __expf(m_run[r] - mn);
      float sum = 0.f;
      float p[4];
#pragma unroll
      for (int tj = 0; tj < 4; ++tj) { p[tj] = __expf(sv[tj] - mn); sum += p[tj]; }
#pragma unroll
      for (int mm = 8; mm >= 1; mm >>= 1) sum += __shfl_xor(sum, mm);
      l_run[r] = l_run[r] * alpha + sum;
      m_run[r] = mn;
#pragma unroll
      for (int td = 0; td < 4; ++td) oacc[td][r] *= alpha;
      const int prow = wr + qq * 4 + r;
      const int pkey = (prow >> 1) & 7;
#pragma unroll
      for (int tj = 0; tj < 4; ++tj)
        ps[prow * PAD + ((((tj * 2 + (c >> 3)) ^ pkey) & 7) << 3) + (c & 7)] = (f16)p[tj];
    }

    const int qrow = wr + c;
    const int qkey = (qrow >> 1) & 7;
    const half8 p0 = *(const half8*)&ps[qrow * PAD + (((qq ^ qkey) & 7) << 3)];
    const half8 p1 = *(const half8*)&ps[qrow * PAD + ((((4 + qq) ^ qkey) & 7) << 3)];
#pragma unroll
    for (int td = 0; td < 4; ++td) {
      const int dv = td * 16 + c;
      const int vkey = (dv >> 3) & 7;
      const half8 b0 = *(const half8*)&vts[dv * PAD + (((qq ^ vkey) & 7) << 3)];
      const half8 b1 = *(const half8*)&vts[dv * PAD + ((((4 + qq) ^ vkey) & 7) << 3)];
      oacc[td] = __builtin_amdgcn_mfma_f32_16x16x32_f16(p0, b0, oacc[td], 0, 0, 0);
      oacc[td] = __builtin_amdgcn_mfma_f32_16x16x32_f16(p1, b1, oacc[td], 0, 0, 0);
    }
  }

  // ---- j==0 global column as a scalar online-softmax step (qt>2 only; for
  // qt<=2 chunk 0 was inside the loop). All rows here satisfy ii>=192>0.
  if (qt > 2) {
    float kk[4], vv[4];
#pragma unroll
    for (int e = 0; e < 4; ++e) kk[e] = k0f[c * 4 + e];
#pragma unroll
    for (int td = 0; td < 4; ++td) vv[td] = v0f[td * 16 + c];
#pragma unroll
    for (int r = 0; r < 4; ++r) {
      const int row = wr + qq * 4 + r;
      float part = 0.f;
#pragma unroll
      for (int e = 0; e < 4; ++e)
        part = fmaf((float)qs[row * PAD + c * 4 + e], kk[e], part);
#pragma unroll
      for (int mm = 8; mm >= 1; mm >>= 1) part += __shfl_xor(part, mm);
      const float s0 = part * 0.125f;
      const float mn = fmaxf(m_run[r], s0);
      const float alpha = __expf(m_run[r] - mn);
      const float p0 = __expf(s0 - mn);
      l_run[r] = l_run[r] * alpha + p0;
      m_run[r] = mn;
#pragma unroll
      for (int td = 0; td < 4; ++td)
        oacc[td][r] = oacc[td][r] * alpha + p0 * vv[td];
    }
  }

#pragma unroll
  for (int td = 0; td < 4; ++td)
#pragma unroll
    for (int r = 0; r < 4; ++r) {
      const int ii = q0 + wr + qq * 4 + r;
      ao[((size_t)(b * Tseq + ii)) * Dm + hh * HDim + td * 16 + c] =
          (f16)(oacc[td][r] / l_run[r]);
    }
}

// Combine NSPLIT partials per (b,h) and write row T-1 of attnF.
__global__ __launch_bounds__(64) void attn_row_comb(const float* __restrict__ part,
                                                    f16* __restrict__ ao) {
  const int bh = blockIdx.x;
  const int b = bh >> 4, hh = bh & 15;
  const int tid = threadIdx.x;
  const float* pp = part + (size_t)bh * NSPLIT * 66;
  float M = -INFINITY;
#pragma unroll
  for (int s = 0; s < NSPLIT; ++s) M = fmaxf(M, pp[s * 66 + 64]);
  float L = 0.f, o = 0.f;
#pragma unroll
  for (int s = 0; s < NSPLIT; ++s) {
    const float wgt = __expf(pp[s * 66 + 64] - M);
    L += pp[s * 66 + 65] * wgt;
    o += pp[s * 66 + tid] * wgt;
  }
  ao[((size_t)(b * Tseq + Tseq - 1)) * Dm + hh * HDim + tid] = (f16)(o / L);
}

// ---------------------------------------------------------------- launch
extern "C" void kernel_launch(void* const* d_in, const int* in_sizes, int n_in,
                              void* d_out, int out_size, void* d_ws, size_t ws_size,
                              hipStream_t stream) {
  (void)in_sizes; (void)n_in; (void)out_size; (void)ws_size;
  const float* x    = (const float*)d_in[0];
  const float* ln1g = (const float*)d_in[1];
  const float* ln1b = (const float*)d_in[2];
  const float* ln2g = (const float*)d_in[3];
  const float* ln2b = (const float*)d_in[4];
  const float* Wq   = (const float*)d_in[5];
  const float* Wk   = (const float*)d_in[6];
  const float* Wv   = (const float*)d_in[7];
  const float* Wo   = (const float*)d_in[8];
  const float* bo   = (const float*)d_in[9];
  const float* W1   = (const float*)d_in[10];
  const float* b1   = (const float*)d_in[11];
  const float* W2   = (const float*)d_in[12];
  const float* b2   = (const float*)d_in[13];
  float* out = (float*)d_out;

  char* w0 = (char*)d_ws;
  size_t off = 0;
  auto take = [&](size_t bytes) -> char* {
    char* p = w0 + off;
    off += (bytes + 255) & ~(size_t)255;
    return p;
  };
  f16*   WqkvT = (f16*)take((size_t)3 * Dm * Dm * 2);  // Wq^T | Wk^T | Wv^T stacked
  f16*   WoT   = (f16*)take((size_t)Dm * Dm * 2);
  f16*   W1T   = (f16*)take((size_t)Dm * 4 * Dm * 2);
  f16*   W2T   = (f16*)take((size_t)Dm * 4 * Dm * 2);
  f16*   hF    = (f16*)take((size_t)Mrows * Dm * 2);
  f16*   qkvh  = (f16*)take((size_t)Mrows * QS * 2);   // 24 MiB
  f16*   attnF = (f16*)take((size_t)Mrows * Dm * 2);   // 8 MiB, contiguous after qkvh
  float* x1    = (float*)take((size_t)Mrows * Dm * 4);
  f16*   h2F   = (f16*)take((size_t)Mrows * Dm * 2);
  f16*   pbuf  = (f16*)take((size_t)4 * Mrows * Dm * 2);  // split-K f16 partials (32 MB)
  float* rowp  = (float*)take((size_t)32 * NSPLIT * 66 * 4);  // global-row partials
  f16*   ffn1F = qkvh;  // 4096x4096 f16 = 32 MiB == qkvh(24) + attnF(8) span

  const dim3 blk(256);

  // prep: 6 transposes + LN1 in one launch (16384 blocks)
  prep<<<dim3(16384), blk, 0, stream>>>(Wq, Wk, Wv, Wo, W1, W2, x, ln1g, ln1b,
                                        WqkvT, WoT, W1T, W2T, hF);

  // fused QKV: (4096x1024)@(1024x3072) -> qkvh; 768 blocks, chunked-XCD bx
  gemm_f16<3, 0><<<dim3(768), blk, 0, stream>>>(
      hF, WqkvT, Mrows, QS, Dm, Dm, nullptr, qkvh);

  // attention: windowed (1024) + global-row split-j partials (512), one launch
  attn_fused<<<dim3(1536), blk, 0, stream>>>(qkvh, attnF, rowp);
  attn_row_comb<<<dim3(2 * NHd), dim3(64), 0, stream>>>(rowp, attnF);

  // Wo: split-K2 f16 partials, flat grid with z in low bits (512 blocks)
  gemm_f16<5, 1><<<dim3(512), blk, 0, stream>>>(
      attnF, WoT, Mrows, Dm, Dm, Dm / 2, nullptr, pbuf);
  reduce_ln<2><<<Mrows, blk, 0, stream>>>(pbuf, x, bo, ln2g, ln2b, x1, h2F);

  // FFN1: N=4096, 1024 blocks, chunked-XCD bx, fast-GELU epilogue
  gemm_f16<2, 0><<<dim3(1024), blk, 0, stream>>>(
      h2F, W1T, Mrows, 4 * Dm, Dm, Dm, b1, ffn1F);

  // W2: split-K4 f16 partials, flat grid (1024 blocks), then out = x1 + b2 + sum(P)
  gemm_f16<5, 2><<<dim3(1024), blk, 0, stream>>>(
      ffn1F, W2T, Mrows, Dm, 4 * Dm, Dm, nullptr, pbuf);
  reduceK<4><<<Mrows * Dm / (256 * 8), blk, 0, stream>>>(pbuf, x1, b2, out);
}